// Round 6
// baseline (1395.437 us; speedup 1.0000x reference)
//
#include <hip/hip_runtime.h>
#include <hip/hip_bf16.h>
#include <cstddef>

// ---------------------------------------------------------------------------
// LSTMSeq2Seq: B=4096, L=64, T=48, H=64, NH=4, HD=16, NQ=3
// Round 6: 2 blocks/CU LSTM (ROWS=8, grid 512) for stall hiding +
// conflict-free row-major gb layout. Attn pipeline unchanged (round-4/5).
// ---------------------------------------------------------------------------

#define B_   4096
#define L_   64
#define T_   48
#define H_   64
#define ROWS 8       // batch rows per LSTM block (was 16)
#define PADH 136     // LSTM A row pad (halves)
#define GBS  260     // gb row stride (floats): bank = (4*row + col) % 32 -> 2-way max

using half8  = __attribute__((ext_vector_type(8))) _Float16;
using half4  = __attribute__((ext_vector_type(4))) _Float16;
using f32x4  = __attribute__((ext_vector_type(4))) float;
using f32x2  = __attribute__((ext_vector_type(2))) float;

#define IC_ 4.8828125e-4f   // 2^-11

// native-rate transcendentals (v_exp_f32 + v_rcp_f32); overflow-safe forms
__device__ __forceinline__ float fsig(float x) {
    return __builtin_amdgcn_rcpf(1.0f + __expf(-x));
}
__device__ __forceinline__ float ftanh(float x) {
    float e = __expf(-2.0f * fabsf(x));            // e in (0,1], never overflows
    float r = (1.0f - e) * __builtin_amdgcn_rcpf(1.0f + e);
    return copysignf(r, x);
}

// ---------------------------------------------------------------------------
// LSTM weight split (one-time): whalf[split][gate_row 256][k 128]
// ---------------------------------------------------------------------------
__global__ void transpose_w_kernel(const float* __restrict__ Wih,
                                   const float* __restrict__ Whh,
                                   _Float16* __restrict__ out) {
    int idx = blockIdx.x * 256 + threadIdx.x;
    if (idx >= 16384) return;
    int r = idx >> 6, k = idx & 63;
    float wi = Wih[idx];
    _Float16 hi = (_Float16)wi;
    out[r * 128 + k] = hi;
    out[32768 + r * 128 + k] = (_Float16)((wi - (float)hi) * 2048.0f);
    float wh = Whh[idx];
    hi = (_Float16)wh;
    out[r * 128 + 64 + k] = hi;
    out[32768 + r * 128 + 64 + k] = (_Float16)((wh - (float)hi) * 2048.0f);
}

// Attention weight splits: wqkvh[2][192][64], woh[2][64][64], w1h[2][32][64]
__global__ void split_aux_kernel(const float* __restrict__ Wqkv,
                                 const float* __restrict__ Wo,
                                 const float* __restrict__ W1,
                                 _Float16* __restrict__ wqkvh,
                                 _Float16* __restrict__ woh,
                                 _Float16* __restrict__ w1h) {
    int idx = blockIdx.x * 256 + threadIdx.x;
    if (idx < 12288) {
        float v = Wqkv[idx]; _Float16 h = (_Float16)v;
        wqkvh[idx] = h; wqkvh[12288 + idx] = (_Float16)((v - (float)h) * 2048.f);
    } else if (idx < 16384) {
        int i = idx - 12288;
        float v = Wo[i]; _Float16 h = (_Float16)v;
        woh[i] = h; woh[4096 + i] = (_Float16)((v - (float)h) * 2048.f);
    } else if (idx < 18432) {
        int i = idx - 16384;
        float v = W1[i]; _Float16 h = (_Float16)v;
        w1h[i] = h; w1h[2048 + i] = (_Float16)((v - (float)h) * 2048.f);
    }
}

// ---------------------------------------------------------------------------
// Fused 2-layer LSTM, skewed; ROWS=8, grid 512 -> 2 blocks/CU.
// Wave w owns gate cols [w*32,(w+1)*32) of BOTH layers; W resident in VGPRs.
// A tiles keep 16-row MFMA layout; rows 8..15 zeroed once (discarded output).
// gb: row-major [8][GBS] -> conflict-free writes, 2-way (free) reads.
// ---------------------------------------------------------------------------
__global__ __launch_bounds__(512, 4) void lstm2_mfma_kernel(
    const float* __restrict__ inseq,
    const float* __restrict__ in0,
    const _Float16* __restrict__ w1half,
    const float* __restrict__ b1ihp, const float* __restrict__ b1hhp,
    const _Float16* __restrict__ w2half,
    const float* __restrict__ b2ihp, const float* __restrict__ b2hhp,
    const float* __restrict__ h01, const float* __restrict__ c01,
    const float* __restrict__ h02, const float* __restrict__ c02,
    float* __restrict__ outseq2,
    float* __restrict__ hf1, float* __restrict__ cf1,
    float* __restrict__ hf2, float* __restrict__ cf2,
    int S, int mode)
{
    __shared__ __align__(16) _Float16 A1[2 * 16 * PADH];   // [plane][row16][k]
    __shared__ __align__(16) _Float16 A2[2 * 16 * PADH];
    __shared__ __align__(16) float gb1[ROWS * GBS];        // [row8][gatecol 256]
    __shared__ __align__(16) float gb2[ROWS * GBS];

    const int tid  = threadIdx.x;
    const int w    = tid >> 6;          // 0..7
    const int l    = tid & 63;
    const int lrow = l & 15;
    const int lkg  = l >> 4;
    const int row0 = blockIdx.x * ROWS;

    half8 w1hi[4][2], w1lo[4][2], w2hi[4][2], w2lo[4][2];
    #pragma unroll
    for (int kt = 0; kt < 4; ++kt)
        #pragma unroll
        for (int nt = 0; nt < 2; ++nt) {
            const int col = w * 32 + nt * 16 + lrow;
            const size_t off = (size_t)col * 128 + kt * 32 + lkg * 8;
            w1hi[kt][nt] = *(const half8*)&w1half[off];
            w1lo[kt][nt] = *(const half8*)&w1half[32768 + off];
            w2hi[kt][nt] = *(const half8*)&w2half[off];
            w2lo[kt][nt] = *(const half8*)&w2half[32768 + off];
        }
    float bs1[2], bs2[2];
    #pragma unroll
    for (int nt = 0; nt < 2; ++nt) {
        const int col = w * 32 + nt * 16 + lrow;
        bs1[nt] = b1ihp[col] + b1hhp[col];
        bs2[nt] = b2ihp[col] + b2hhp[col];
    }

    const int rx = tid >> 6, jx = tid & 63;   // staging: 1 value/thread
    const int ju = tid & 63, ru = tid >> 6;   // cell: col ju, row ru (0..7)

    // ---- prologue: zero rows 8..15 of A1/A2 (both planes) ------------------
    for (int o = tid; o < 8 * PADH; o += 512) {
        A1[8 * PADH + o] = (_Float16)0.f;
        A1[24 * PADH + o] = (_Float16)0.f;
        A2[8 * PADH + o] = (_Float16)0.f;
        A2[24 * PADH + o] = (_Float16)0.f;
    }
    // stage x(0) | h01 into A1; h02 into A2; load c's
    {
        const float* p0 = (mode == 1) ? (in0 + (size_t)(row0 + rx) * 64)
                                      : (inseq + (size_t)(row0 + rx) * S * 64);
        float v = p0[jx];
        _Float16 hi = (_Float16)v;
        A1[rx * PADH + jx] = hi;
        A1[16 * PADH + rx * PADH + jx] = (_Float16)((v - (float)hi) * 2048.f);
    }
    float c1, c2, h1l = 0.f, h2l = 0.f;
    {
        float hv1 = h01 ? h01[(size_t)(row0 + ru) * 64 + ju] : 0.f;
        _Float16 hh = (_Float16)hv1;
        A1[ru * PADH + 64 + ju] = hh;
        A1[16 * PADH + ru * PADH + 64 + ju] = (_Float16)((hv1 - (float)hh) * 2048.f);
        c1 = c01 ? c01[(size_t)(row0 + ru) * 64 + ju] : 0.f;
        float hv2 = h02 ? h02[(size_t)(row0 + ru) * 64 + ju] : 0.f;
        hh = (_Float16)hv2;
        A2[ru * PADH + 64 + ju] = hh;
        A2[16 * PADH + ru * PADH + 64 + ju] = (_Float16)((hv2 - (float)hh) * 2048.f);
        c2 = c02 ? c02[(size_t)(row0 + ru) * 64 + ju] : 0.f;
    }

    const int aoff = lrow * PADH + lkg * 8;

    for (int i = 0; i <= S; ++i) {
        __syncthreads();   // A1/A2 ready; prev gb consumers done
        const bool doL1 = (i < S), doL2 = (i > 0);

        // prefetch x(i+1) (1 f32/thread); drains under the GEMM phase
        float xn = 0.f;
        if (i + 1 < S) {
            const float* pn = (mode == 1)
                ? (inseq + ((size_t)(row0 + rx) * S + i) * 64)        // target[i]
                : (inseq + ((size_t)(row0 + rx) * S + (i + 1)) * 64);
            xn = pn[jx];
        }

        if (doL1) {   // GEMM1: gates1 = A1 @ W1^T
            f32x4 a0[2], a1[2];
            #pragma unroll
            for (int nt = 0; nt < 2; ++nt) {
                a0[nt] = (f32x4){bs1[nt], bs1[nt], bs1[nt], bs1[nt]};
                a1[nt] = (f32x4){0.f, 0.f, 0.f, 0.f};
            }
            #pragma unroll
            for (int kt = 0; kt < 4; ++kt) {
                half8 ah = *(const half8*)&A1[aoff + kt * 32];
                half8 al = *(const half8*)&A1[16 * PADH + aoff + kt * 32];
                #pragma unroll
                for (int nt = 0; nt < 2; ++nt) {
                    a0[nt] = __builtin_amdgcn_mfma_f32_16x16x32_f16(ah, w1hi[kt][nt], a0[nt], 0, 0, 0);
                    a1[nt] = __builtin_amdgcn_mfma_f32_16x16x32_f16(ah, w1lo[kt][nt], a1[nt], 0, 0, 0);
                    a1[nt] = __builtin_amdgcn_mfma_f32_16x16x32_f16(al, w1hi[kt][nt], a1[nt], 0, 0, 0);
                }
            }
            if (lkg < 2) {   // only rows 0..7 are real
                #pragma unroll
                for (int nt = 0; nt < 2; ++nt) {
                    f32x4 g = a0[nt] + a1[nt] * IC_;
                    const int col = w * 32 + nt * 16 + lrow;
                    #pragma unroll
                    for (int q = 0; q < 4; ++q)
                        gb1[(lkg * 4 + q) * GBS + col] = g[q];
                }
            }
        }
        if (doL2) {   // GEMM2: gates2 = A2 @ W2^T
            f32x4 a0[2], a1[2];
            #pragma unroll
            for (int nt = 0; nt < 2; ++nt) {
                a0[nt] = (f32x4){bs2[nt], bs2[nt], bs2[nt], bs2[nt]};
                a1[nt] = (f32x4){0.f, 0.f, 0.f, 0.f};
            }
            #pragma unroll
            for (int kt = 0; kt < 4; ++kt) {
                half8 ah = *(const half8*)&A2[aoff + kt * 32];
                half8 al = *(const half8*)&A2[16 * PADH + aoff + kt * 32];
                #pragma unroll
                for (int nt = 0; nt < 2; ++nt) {
                    a0[nt] = __builtin_amdgcn_mfma_f32_16x16x32_f16(ah, w2hi[kt][nt], a0[nt], 0, 0, 0);
                    a1[nt] = __builtin_amdgcn_mfma_f32_16x16x32_f16(ah, w2lo[kt][nt], a1[nt], 0, 0, 0);
                    a1[nt] = __builtin_amdgcn_mfma_f32_16x16x32_f16(al, w2hi[kt][nt], a1[nt], 0, 0, 0);
                }
            }
            if (lkg < 2) {
                #pragma unroll
                for (int nt = 0; nt < 2; ++nt) {
                    f32x4 g = a0[nt] + a1[nt] * IC_;
                    const int col = w * 32 + nt * 16 + lrow;
                    #pragma unroll
                    for (int q = 0; q < 4; ++q)
                        gb2[(lkg * 4 + q) * GBS + col] = g[q];
                }
            }
        }
        __syncthreads();   // gb ready; A reads drained

        if (doL1) {   // cell1 (row ru): h1(i) -> A1 h-part AND A2 x-part
            float gi = gb1[ru * GBS +   0 + ju];
            float gf = gb1[ru * GBS +  64 + ju];
            float gg = gb1[ru * GBS + 128 + ju];
            float go = gb1[ru * GBS + 192 + ju];
            c1 = fsig(gf) * c1 + fsig(gi) * ftanh(gg);
            float hv = fsig(go) * ftanh(c1);
            h1l = hv;
            _Float16 hh = (_Float16)hv;
            _Float16 hl = (_Float16)((hv - (float)hh) * 2048.f);
            A1[ru * PADH + 64 + ju] = hh;
            A1[16 * PADH + ru * PADH + 64 + ju] = hl;
            A2[ru * PADH + ju] = hh;
            A2[16 * PADH + ru * PADH + ju] = hl;
            if (i + 1 < S) {   // stage x(i+1)
                _Float16 xh = (_Float16)xn;
                A1[rx * PADH + jx] = xh;
                A1[16 * PADH + rx * PADH + jx] = (_Float16)((xn - (float)xh) * 2048.f);
            }
        }
        if (doL2) {   // cell2 (row ru): h2(i-1) -> A2 h-part + outseq2
            float gi = gb2[ru * GBS +   0 + ju];
            float gf = gb2[ru * GBS +  64 + ju];
            float gg = gb2[ru * GBS + 128 + ju];
            float go = gb2[ru * GBS + 192 + ju];
            c2 = fsig(gf) * c2 + fsig(gi) * ftanh(gg);
            float hv = fsig(go) * ftanh(c2);
            h2l = hv;
            _Float16 hh = (_Float16)hv;
            A2[ru * PADH + 64 + ju] = hh;
            A2[16 * PADH + ru * PADH + 64 + ju] = (_Float16)((hv - (float)hh) * 2048.f);
            outseq2[((size_t)(row0 + ru) * S + (i - 1)) * 64 + ju] = hv;
        }
    }
    if (hf1) {
        hf1[(size_t)(row0 + ru) * 64 + ju] = h1l;
        cf1[(size_t)(row0 + ru) * 64 + ju] = c1;
        hf2[(size_t)(row0 + ru) * 64 + ju] = h2l;
        cf2[(size_t)(row0 + ru) * 64 + ju] = c2;
    }
}

// ---------------------------------------------------------------------------
// Helper: stage a fp32 row-block into hi/lo fp16 LDS planes [R][72] (attn0)
// ---------------------------------------------------------------------------
__device__ __forceinline__ void stage_split(const float* __restrict__ src,
                                            _Float16* dst, int plane,
                                            int row, int c0) {
    #pragma unroll
    for (int u = 0; u < 4; ++u) {
        float4 v = *(const float4*)(src + u * 4);
        half4 hi, lo;
        hi[0] = (_Float16)v.x; lo[0] = (_Float16)((v.x - (float)hi[0]) * 2048.f);
        hi[1] = (_Float16)v.y; lo[1] = (_Float16)((v.y - (float)hi[1]) * 2048.f);
        hi[2] = (_Float16)v.z; lo[2] = (_Float16)((v.z - (float)hi[2]) * 2048.f);
        hi[3] = (_Float16)v.w; lo[3] = (_Float16)((v.w - (float)hi[3]) * 2048.f);
        *(half4*)&dst[row * 72 + c0 + u * 4] = hi;
        *(half4*)&dst[plane + row * 72 + c0 + u * 4] = lo;
    }
}

// ---------------------------------------------------------------------------
// Self-attention, last query only (round-3 known-good).
// ---------------------------------------------------------------------------
__global__ __launch_bounds__(256) void attn0_mfma(
    const float* __restrict__ encout,
    const _Float16* __restrict__ wqkvh,
    const float* __restrict__ bqkv,
    const float* __restrict__ Wqkv,
    const float* __restrict__ Wo,
    const float* __restrict__ bo,
    float* __restrict__ a0last)
{
    __shared__ __align__(16) _Float16 E16[2 * 4608];
    __shared__ __align__(16) _Float16 K16[2 * 4608];
    __shared__ __align__(16) _Float16 V16[4608];
    __shared__ float qv[64];
    __shared__ float wrow[4 * 68];
    __shared__ float ov[64];

    const int b = blockIdx.x, tid = threadIdx.x;
    const int w = tid >> 6, l = tid & 63, lr = l & 15, lkg = l >> 4;

    {
        int row = tid >> 2, c0 = (tid & 3) * 16;
        stage_split(encout + (size_t)b * 4096 + row * 64 + c0, E16, 4608, row, c0);
    }
    __syncthreads();

    for (int tt = w; tt < 8; tt += 4) {
        const int kind = (tt < 4) ? 0 : 1;
        const int mrow = (kind ? tt - 4 : tt) * 16;
        const int wrowB = kind ? 128 : 64;
        half8 ah[2], al[2];
        #pragma unroll
        for (int kt = 0; kt < 2; ++kt) {
            int ao = (mrow + lr) * 72 + kt * 32 + lkg * 8;
            ah[kt] = *(const half8*)&E16[ao];
            al[kt] = *(const half8*)&E16[4608 + ao];
        }
        #pragma unroll
        for (int nt = 0; nt < 4; ++nt) {
            const int col = nt * 16 + lr;
            const float bv = bqkv[wrowB + col];
            f32x4 a0 = (f32x4){bv, bv, bv, bv};
            f32x4 a1 = (f32x4){0.f, 0.f, 0.f, 0.f};
            #pragma unroll
            for (int kt = 0; kt < 2; ++kt) {
                const _Float16* wp = wqkvh + (size_t)(wrowB + col) * 64 + kt * 32 + lkg * 8;
                half8 bh = *(const half8*)wp;
                half8 bl = *(const half8*)(wp + 12288);
                a0 = __builtin_amdgcn_mfma_f32_16x16x32_f16(ah[kt], bh, a0, 0, 0, 0);
                a1 = __builtin_amdgcn_mfma_f32_16x16x32_f16(ah[kt], bl, a1, 0, 0, 0);
                a1 = __builtin_amdgcn_mfma_f32_16x16x32_f16(al[kt], bh, a1, 0, 0, 0);
            }
            #pragma unroll
            for (int i = 0; i < 4; ++i) {
                float g = a0[i] + a1[i] * IC_;
                int r = mrow + lkg * 4 + i;
                if (kind == 0) {
                    _Float16 gh = (_Float16)g;
                    K16[r * 72 + col] = gh;
                    K16[4608 + r * 72 + col] = (_Float16)((g - (float)gh) * 2048.f);
                } else {
                    V16[r * 72 + col] = (_Float16)g;
                }
            }
        }
    }
    if (w == 3) {
        float a = bqkv[l];
        for (int k = 0; k < 64; ++k) {
            float e = (float)E16[63 * 72 + k] + (float)E16[4608 + 63 * 72 + k] * IC_;
            a += e * Wqkv[l * 64 + k];
        }
        qv[l] = a;
    }
    __syncthreads();

    {
        const int h = tid >> 6, kv = tid & 63;
        float s = 0.f;
        #pragma unroll
        for (int d = 0; d < 16; ++d) {
            float kk = (float)K16[kv * 72 + h * 16 + d]
                     + (float)K16[4608 + kv * 72 + h * 16 + d] * IC_;
            s += qv[h * 16 + d] * kk;
        }
        s *= 0.25f;
        float m = s;
        #pragma unroll
        for (int off = 32; off; off >>= 1) m = fmaxf(m, __shfl_xor(m, off));
        float e = __expf(s - m);
        float sum = e;
        #pragma unroll
        for (int off = 32; off; off >>= 1) sum += __shfl_xor(sum, off);
        wrow[h * 68 + kv] = e / sum;
    }
    __syncthreads();
    if (tid < 64) {
        const int h = tid >> 4, d = tid & 15;
        float o = 0.f;
        for (int kv = 0; kv < 64; ++kv)
            o += wrow[h * 68 + kv] * (float)V16[kv * 72 + h * 16 + d];
        ov[tid] = o;
    }
    __syncthreads();
    if (tid < 64) {
        float a = bo[tid];
        for (int k = 0; k < 64; ++k) a += ov[k] * Wo[tid * 64 + k];
        a0last[(size_t)b * 64 + tid] = a;
    }
}

// ---------------------------------------------------------------------------
// Cross-attention v2 (round-4 known-good): one b per block, S^T scores,
// no atomics, 4 barriers, 40960 B dynamic LDS.
// ---------------------------------------------------------------------------
__global__ __launch_bounds__(256, 4) void cross_attn_v2(
    const float* __restrict__ encout, const float* __restrict__ decout,
    const _Float16* __restrict__ wqkvh, const float* __restrict__ bqkv,
    _Float16* __restrict__ AOg, float* __restrict__ attnw)
{
    extern __shared__ __align__(16) char smem[];
    _Float16* E  = (_Float16*)(smem);
    _Float16* D  = (_Float16*)(smem + 9216);
    _Float16* K  = (_Float16*)(smem + 16128);
    _Float16* Q  = (_Float16*)(smem + 25344);
    _Float16* VT = (_Float16*)(smem + 32256);

    const int b = blockIdx.x, tid = threadIdx.x;
    const int w = tid >> 6, l = tid & 63, lr = l & 15, lkg = l >> 4;
    const int h = w;

    {
        int row = tid >> 2, c0 = (tid & 3) * 16;
        const float* ep = encout + (size_t)b * 4096 + row * 64 + c0;
        half8 v0, v1;
        #pragma unroll
        for (int j = 0; j < 8; ++j) v0[j] = (_Float16)ep[j];
        #pragma unroll
        for (int j = 0; j < 8; ++j) v1[j] = (_Float16)ep[8 + j];
        *(half8*)&E[row * 72 + c0] = v0;
        *(half8*)&E[row * 72 + c0 + 8] = v1;
        if (row < 48) {
            const float* dp = decout + (size_t)b * 3072 + row * 64 + c0;
            half8 u0, u1;
            #pragma unroll
            for (int j = 0; j < 8; ++j) u0[j] = (_Float16)dp[j];
            #pragma unroll
            for (int j = 0; j < 8; ++j) u1[j] = (_Float16)dp[8 + j];
            *(half8*)&D[row * 72 + c0] = u0;
            *(half8*)&D[row * 72 + c0 + 8] = u1;
        }
    }
    __syncthreads();

    for (int tt = w; tt < 11; tt += 4) {
        const int kind = (tt < 4) ? 0 : ((tt < 8) ? 1 : 2);
        const int mrow = ((kind == 0) ? tt : (kind == 1) ? tt - 4 : tt - 8) * 16;
        const int wrowB = (kind == 0) ? 64 : ((kind == 1) ? 128 : 0);
        const _Float16* S = (kind == 2) ? D : E;
        half8 ah[2];
        #pragma unroll
        for (int kt = 0; kt < 2; ++kt)
            ah[kt] = *(const half8*)&S[(mrow + lr) * 72 + kt * 32 + lkg * 8];
        #pragma unroll
        for (int nt = 0; nt < 4; ++nt) {
            const int col = nt * 16 + lr;
            const float bv = bqkv[wrowB + col];
            f32x4 a0 = (f32x4){bv, bv, bv, bv};
            #pragma unroll
            for (int kt = 0; kt < 2; ++kt) {
                half8 bh = *(const half8*)&wqkvh[(size_t)(wrowB + col) * 64 + kt * 32 + lkg * 8];
                a0 = __builtin_amdgcn_mfma_f32_16x16x32_f16(ah[kt], bh, a0, 0, 0, 0);
            }
            if (kind == 1) {
                half4 p;
                #pragma unroll
                for (int i = 0; i < 4; ++i) p[i] = (_Float16)a0[i];
                *(half4*)&VT[col * 68 + mrow + lkg * 4] = p;
            } else {
                _Float16* dst = (kind == 0) ? K : Q;
                #pragma unroll
                for (int i = 0; i < 4; ++i)
                    dst[(mrow + lkg * 4 + i) * 72 + col] = (_Float16)a0[i];
            }
        }
    }
    __syncthreads();

    const half8 z = {0, 0, 0, 0, 0, 0, 0, 0};
    half8 ka[4], qb[3];
    #pragma unroll
    for (int kvt = 0; kvt < 4; ++kvt)
        ka[kvt] = (lkg < 2) ? *(const half8*)&K[(kvt * 16 + lr) * 72 + h * 16 + lkg * 8] : z;
    #pragma unroll
    for (int qt = 0; qt < 3; ++qt)
        qb[qt] = (lkg < 2) ? *(const half8*)&Q[(qt * 16 + lr) * 72 + h * 16 + lkg * 8] : z;
    __syncthreads();

    _Float16* strip = (_Float16*)(smem + ((h == 0) ? 0 : (h == 1) ? 9216
                                        : (h == 2) ? 16128 : 25344));
    {
        f32x4 s[3][4];
        #pragma unroll
        for (int qt = 0; qt < 3; ++qt) {
            #pragma unroll
            for (int kvt = 0; kvt < 4; ++kvt) {
                f32x4 a0 = (f32x4){0.f, 0.f, 0.f, 0.f};
                a0 = __builtin_amdgcn_mfma_f32_16x16x32_f16(ka[kvt], qb[qt], a0, 0, 0, 0);
                s[qt][kvt] = a0 * 0.25f;
            }
            float m = s[qt][0][0];
            #pragma unroll
            for (int kvt = 0; kvt < 4; ++kvt)
                #pragma unroll
                for (int i = 0; i < 4; ++i) m = fmaxf(m, s[qt][kvt][i]);
            m = fmaxf(m, __shfl_xor(m, 16));
            m = fmaxf(m, __shfl_xor(m, 32));
            float sum = 0.f;
            #pragma unroll
            for (int kvt = 0; kvt < 4; ++kvt)
                #pragma unroll
                for (int i = 0; i < 4; ++i) {
                    float e = __expf(s[qt][kvt][i] - m);
                    s[qt][kvt][i] = e;
                    sum += e;
                }
            sum += __shfl_xor(sum, 16);
            sum += __shfl_xor(sum, 32);
            const float r = 1.0f / sum;
            #pragma unroll
            for (int kvt = 0; kvt < 4; ++kvt) {
                half4 p;
                #pragma unroll
                for (int i = 0; i < 4; ++i) p[i] = (_Float16)(s[qt][kvt][i] * r);
                *(half4*)&strip[(qt * 16 + lr) * 72 + kvt * 16 + lkg * 4] = p;
            }
        }
    }
    {
        half8 vb[2];
        #pragma unroll
        for (int kt = 0; kt < 2; ++kt) {
            half4 lo4 = *(const half4*)&VT[(h * 16 + lr) * 68 + kt * 32 + lkg * 8];
            half4 hi4 = *(const half4*)&VT[(h * 16 + lr) * 68 + kt * 32 + lkg * 8 + 4];
            #pragma unroll
            for (int j = 0; j < 4; ++j) { vb[kt][j] = lo4[j]; vb[kt][4 + j] = hi4[j]; }
        }
        #pragma unroll
        for (int qt = 0; qt < 3; ++qt) {
            f32x4 acc = (f32x4){0.f, 0.f, 0.f, 0.f};
            #pragma unroll
            for (int kt = 0; kt < 2; ++kt) {
                half8 wa = *(const half8*)&strip[(qt * 16 + lr) * 72 + kt * 32 + lkg * 8];
                acc = __builtin_amdgcn_mfma_f32_16x16x32_f16(wa, vb[kt], acc, 0, 0, 0);
            }
            #pragma unroll
            for (int i = 0; i < 4; ++i)
                AOg[((size_t)b * 48 + qt * 16 + lkg * 4 + i) * 64 + h * 16 + lr] =
                    (_Float16)acc[i];
        }
    }
    __syncthreads();

    {
        const _Float16* s0 = (const _Float16*)(smem);
        const _Float16* s1 = (const _Float16*)(smem + 9216);
        const _Float16* s2 = (const _Float16*)(smem + 16128);
        const _Float16* s3 = (const _Float16*)(smem + 25344);
        #pragma unroll
        for (int it = 0; it < 12; ++it) {
            int idx = tid + it * 256;
            int o = (idx >> 6) * 72 + (idx & 63);
            attnw[(size_t)b * 3072 + idx] =
                0.25f * ((float)s0[o] + (float)s1[o] + (float)s2[o] + (float)s3[o]);
        }
    }
}

// ---------------------------------------------------------------------------
// Batched out-proj + FC1(relu) + FC2. 64 rows/block, zero barriers.
// ---------------------------------------------------------------------------
__global__ __launch_bounds__(256) void proj_fc_kernel(
    const _Float16* __restrict__ AOg,
    const _Float16* __restrict__ woh, const float* __restrict__ bo,
    const _Float16* __restrict__ w1h, const float* __restrict__ b1,
    const float* __restrict__ W2,     const float* __restrict__ b2,
    float* __restrict__ pred)
{
    __shared__ __align__(16) _Float16 obuf[4][16 * 72];
    __shared__ float h1buf[4][16 * 36];
    const int tid = threadIdx.x;
    const int w = tid >> 6, l = tid & 63, lr = l & 15, lkg = l >> 4;
    const size_t r0 = (size_t)blockIdx.x * 64 + w * 16;

    half8 ah[2];
    #pragma unroll
    for (int kt = 0; kt < 2; ++kt)
        ah[kt] = *(const half8*)&AOg[(r0 + lr) * 64 + kt * 32 + lkg * 8];
    #pragma unroll
    for (int nt = 0; nt < 4; ++nt) {
        const int col = nt * 16 + lr;
        const float bv = bo[col];
        f32x4 a0 = (f32x4){bv, bv, bv, bv};
        #pragma unroll
        for (int kt = 0; kt < 2; ++kt) {
            half8 bh = *(const half8*)&woh[(size_t)col * 64 + kt * 32 + lkg * 8];
            a0 = __builtin_amdgcn_mfma_f32_16x16x32_f16(ah[kt], bh, a0, 0, 0, 0);
        }
        #pragma unroll
        for (int i = 0; i < 4; ++i)
            obuf[w][(lkg * 4 + i) * 72 + col] = (_Float16)a0[i];
    }
    half8 oh[2];
    #pragma unroll
    for (int kt = 0; kt < 2; ++kt)
        oh[kt] = *(const half8*)&obuf[w][lr * 72 + kt * 32 + lkg * 8];
    #pragma unroll
    for (int nt = 0; nt < 2; ++nt) {
        const int m = nt * 16 + lr;
        const float bv = b1[m];
        f32x4 a0 = (f32x4){bv, bv, bv, bv};
        #pragma unroll
        for (int kt = 0; kt < 2; ++kt) {
            half8 bh = *(const half8*)&w1h[(size_t)m * 64 + kt * 32 + lkg * 8];
            a0 = __builtin_amdgcn_mfma_f32_16x16x32_f16(oh[kt], bh, a0, 0, 0, 0);
        }
        #pragma unroll
        for (int i = 0; i < 4; ++i)
            h1buf[w][(lkg * 4 + i) * 36 + m] = fmaxf(a0[i], 0.f);
    }
    if (l < 48) {
        const int q = l / 3, n = l - 3 * q;
        float a = b2[n];
        #pragma unroll
        for (int m2 = 0; m2 < 32; ++m2)
            a += h1buf[w][q * 36 + m2] * W2[n * 32 + m2];
        pred[(r0 + q) * 3 + n] = a;
    }
}

// ---------------------------------------------------------------------------
extern "C" void kernel_launch(void* const* d_in, const int* in_sizes, int n_in,
                              void* d_out, int out_size, void* d_ws, size_t ws_size,
                              hipStream_t stream) {
    const float* x      = (const float*)d_in[0];
    const float* target = (const float*)d_in[1];
    const float* eWih0 = (const float*)d_in[2],  *eWhh0 = (const float*)d_in[3];
    const float* ebih0 = (const float*)d_in[4],  *ebhh0 = (const float*)d_in[5];
    const float* eWih1 = (const float*)d_in[6],  *eWhh1 = (const float*)d_in[7];
    const float* ebih1 = (const float*)d_in[8],  *ebhh1 = (const float*)d_in[9];
    const float* dWih0 = (const float*)d_in[10], *dWhh0 = (const float*)d_in[11];
    const float* dbih0 = (const float*)d_in[12], *dbhh0 = (const float*)d_in[13];
    const float* dWih1 = (const float*)d_in[14], *dWhh1 = (const float*)d_in[15];
    const float* dbih1 = (const float*)d_in[16], *dbhh1 = (const float*)d_in[17];
    const float* Wqkv = (const float*)d_in[18], *bqkv = (const float*)d_in[19];
    const float* Wo   = (const float*)d_in[20], *bo   = (const float*)d_in[21];
    const float* W1   = (const float*)d_in[22], *b1   = (const float*)d_in[23];
    const float* W2   = (const float*)d_in[24], *b2   = (const float*)d_in[25];

    float* ws = (float*)d_ws;
    float* hseq1  = ws;                                   // AOg alias region
    float* encout = hseq1  + (size_t)B_ * L_ * H_;
    float* decout = encout + (size_t)B_ * L_ * H_;
    float* a0last = decout + (size_t)B_ * T_ * H_;
    float* hfin   = a0last + (size_t)B_ * H_;
    float* cfin   = hfin   + (size_t)2 * B_ * H_;
    float* wtg    = cfin   + (size_t)2 * B_ * H_;
    float* auxw   = wtg    + (size_t)4 * 32768;

    _Float16* wh0 = (_Float16*)(wtg);
    _Float16* wh1 = wh0 + 65536;
    _Float16* wh2 = wh1 + 65536;
    _Float16* wh3 = wh2 + 65536;
    _Float16* wqkvh = (_Float16*)auxw;        // [2][192][64]
    _Float16* woh   = wqkvh + 24576;          // [2][64][64]
    _Float16* w1h   = woh + 8192;             // [2][32][64]
    _Float16* AOg   = (_Float16*)hseq1;

    float* pred  = (float*)d_out;
    float* attnw = pred + (size_t)B_ * T_ * 3;

    transpose_w_kernel<<<64, 256, 0, stream>>>(eWih0, eWhh0, wh0);
    transpose_w_kernel<<<64, 256, 0, stream>>>(eWih1, eWhh1, wh1);
    transpose_w_kernel<<<64, 256, 0, stream>>>(dWih0, dWhh0, wh2);
    transpose_w_kernel<<<64, 256, 0, stream>>>(dWih1, dWhh1, wh3);
    split_aux_kernel<<<72, 256, 0, stream>>>(Wqkv, Wo, W1, wqkvh, woh, w1h);

    // fused encoder (both layers, skewed); 512 blocks -> 2/CU
    lstm2_mfma_kernel<<<B_ / ROWS, 512, 0, stream>>>(
        x, nullptr, wh0, ebih0, ebhh0, wh1, ebih1, ebhh1,
        nullptr, nullptr, nullptr, nullptr,
        encout, hfin, cfin, hfin + (size_t)B_ * H_, cfin + (size_t)B_ * H_, L_, 0);
    // self-attn, last query
    attn0_mfma<<<B_, 256, 0, stream>>>(encout, wqkvh, bqkv, Wqkv, Wo, bo, a0last);
    // fused decoder
    lstm2_mfma_kernel<<<B_ / ROWS, 512, 0, stream>>>(
        target, a0last, wh2, dbih0, dbhh0, wh3, dbih1, dbhh1,
        hfin, cfin, hfin + (size_t)B_ * H_, cfin + (size_t)B_ * H_,
        decout, nullptr, nullptr, nullptr, nullptr, T_, 1);
    // cross-attention -> AOg, attnw
    cross_attn_v2<<<B_, 256, 40960, stream>>>(
        encout, decout, wqkvh, bqkv, AOg, attnw);
    // out-proj + FC1 + FC2 -> pred
    proj_fc_kernel<<<(B_ * T_) / 64, 256, 0, stream>>>(
        AOg, woh, bo, w1h, b1, W2, b2, pred);
}

// Round 7
// 651.597 us; speedup vs baseline: 2.1416x; 2.1416x over previous
//
#include <hip/hip_runtime.h>
#include <hip/hip_bf16.h>
#include <cstddef>

// ---------------------------------------------------------------------------
// LSTMSeq2Seq: B=4096, L=64, T=48, H=64, NH=4, HD=16, NQ=3
// Round 7: ROWS=8 / grid-512 LSTM (2 blocks/CU) with launch_bounds(512,1) —
// round 6's structure minus the 64-VGPR spill cap. Attn chain unchanged.
// ---------------------------------------------------------------------------

#define B_   4096
#define L_   64
#define T_   48
#define H_   64
#define ROWS 8       // batch rows per LSTM block
#define PADH 136     // LSTM A row pad (halves)
#define GBS  260     // gb row stride (floats)

using half8  = __attribute__((ext_vector_type(8))) _Float16;
using half4  = __attribute__((ext_vector_type(4))) _Float16;
using f32x4  = __attribute__((ext_vector_type(4))) float;
using f32x2  = __attribute__((ext_vector_type(2))) float;

#define IC_ 4.8828125e-4f   // 2^-11

// native-rate transcendentals (v_exp_f32 + v_rcp_f32); overflow-safe forms
__device__ __forceinline__ float fsig(float x) {
    return __builtin_amdgcn_rcpf(1.0f + __expf(-x));
}
__device__ __forceinline__ float ftanh(float x) {
    float e = __expf(-2.0f * fabsf(x));            // e in (0,1], never overflows
    float r = (1.0f - e) * __builtin_amdgcn_rcpf(1.0f + e);
    return copysignf(r, x);
}

// ---------------------------------------------------------------------------
// LSTM weight split (one-time): whalf[split][gate_row 256][k 128]
// ---------------------------------------------------------------------------
__global__ void transpose_w_kernel(const float* __restrict__ Wih,
                                   const float* __restrict__ Whh,
                                   _Float16* __restrict__ out) {
    int idx = blockIdx.x * 256 + threadIdx.x;
    if (idx >= 16384) return;
    int r = idx >> 6, k = idx & 63;
    float wi = Wih[idx];
    _Float16 hi = (_Float16)wi;
    out[r * 128 + k] = hi;
    out[32768 + r * 128 + k] = (_Float16)((wi - (float)hi) * 2048.0f);
    float wh = Whh[idx];
    hi = (_Float16)wh;
    out[r * 128 + 64 + k] = hi;
    out[32768 + r * 128 + 64 + k] = (_Float16)((wh - (float)hi) * 2048.0f);
}

// Attention weight splits: wqkvh[2][192][64], woh[2][64][64], w1h[2][32][64]
__global__ void split_aux_kernel(const float* __restrict__ Wqkv,
                                 const float* __restrict__ Wo,
                                 const float* __restrict__ W1,
                                 _Float16* __restrict__ wqkvh,
                                 _Float16* __restrict__ woh,
                                 _Float16* __restrict__ w1h) {
    int idx = blockIdx.x * 256 + threadIdx.x;
    if (idx < 12288) {
        float v = Wqkv[idx]; _Float16 h = (_Float16)v;
        wqkvh[idx] = h; wqkvh[12288 + idx] = (_Float16)((v - (float)h) * 2048.f);
    } else if (idx < 16384) {
        int i = idx - 12288;
        float v = Wo[i]; _Float16 h = (_Float16)v;
        woh[i] = h; woh[4096 + i] = (_Float16)((v - (float)h) * 2048.f);
    } else if (idx < 18432) {
        int i = idx - 16384;
        float v = W1[i]; _Float16 h = (_Float16)v;
        w1h[i] = h; w1h[2048 + i] = (_Float16)((v - (float)h) * 2048.f);
    }
}

// ---------------------------------------------------------------------------
// Fused 2-layer LSTM, skewed; ROWS=8, grid 512 -> 2 blocks/CU (independent
// barrier groups anti-phase and hide each other's stalls).
// NOTE: launch_bounds min-waves arg MUST stay 1 — (512,4) capped VGPRs at 64
// and spilled the resident weight fragments to scratch (round 6: 2.4 GB HBM).
// ---------------------------------------------------------------------------
__global__ __launch_bounds__(512, 1) void lstm2_mfma_kernel(
    const float* __restrict__ inseq,
    const float* __restrict__ in0,
    const _Float16* __restrict__ w1half,
    const float* __restrict__ b1ihp, const float* __restrict__ b1hhp,
    const _Float16* __restrict__ w2half,
    const float* __restrict__ b2ihp, const float* __restrict__ b2hhp,
    const float* __restrict__ h01, const float* __restrict__ c01,
    const float* __restrict__ h02, const float* __restrict__ c02,
    float* __restrict__ outseq2,
    float* __restrict__ hf1, float* __restrict__ cf1,
    float* __restrict__ hf2, float* __restrict__ cf2,
    int S, int mode)
{
    __shared__ __align__(16) _Float16 A1[2 * 16 * PADH];   // [plane][row16][k]
    __shared__ __align__(16) _Float16 A2[2 * 16 * PADH];
    __shared__ __align__(16) float gb1[ROWS * GBS];        // [row8][gatecol 256]
    __shared__ __align__(16) float gb2[ROWS * GBS];

    const int tid  = threadIdx.x;
    const int w    = tid >> 6;          // 0..7
    const int l    = tid & 63;
    const int lrow = l & 15;
    const int lkg  = l >> 4;
    const int row0 = blockIdx.x * ROWS;

    half8 w1hi[4][2], w1lo[4][2], w2hi[4][2], w2lo[4][2];
    #pragma unroll
    for (int kt = 0; kt < 4; ++kt)
        #pragma unroll
        for (int nt = 0; nt < 2; ++nt) {
            const int col = w * 32 + nt * 16 + lrow;
            const size_t off = (size_t)col * 128 + kt * 32 + lkg * 8;
            w1hi[kt][nt] = *(const half8*)&w1half[off];
            w1lo[kt][nt] = *(const half8*)&w1half[32768 + off];
            w2hi[kt][nt] = *(const half8*)&w2half[off];
            w2lo[kt][nt] = *(const half8*)&w2half[32768 + off];
        }
    float bs1[2], bs2[2];
    #pragma unroll
    for (int nt = 0; nt < 2; ++nt) {
        const int col = w * 32 + nt * 16 + lrow;
        bs1[nt] = b1ihp[col] + b1hhp[col];
        bs2[nt] = b2ihp[col] + b2hhp[col];
    }

    const int rx = tid >> 6, jx = tid & 63;   // staging: 1 value/thread
    const int ju = tid & 63, ru = tid >> 6;   // cell: col ju, row ru (0..7)

    // ---- prologue: zero rows 8..15 of A1/A2 (both planes) ------------------
    for (int o = tid; o < 8 * PADH; o += 512) {
        A1[8 * PADH + o] = (_Float16)0.f;
        A1[24 * PADH + o] = (_Float16)0.f;
        A2[8 * PADH + o] = (_Float16)0.f;
        A2[24 * PADH + o] = (_Float16)0.f;
    }
    // stage x(0) | h01 into A1; h02 into A2; load c's
    {
        const float* p0 = (mode == 1) ? (in0 + (size_t)(row0 + rx) * 64)
                                      : (inseq + (size_t)(row0 + rx) * S * 64);
        float v = p0[jx];
        _Float16 hi = (_Float16)v;
        A1[rx * PADH + jx] = hi;
        A1[16 * PADH + rx * PADH + jx] = (_Float16)((v - (float)hi) * 2048.f);
    }
    float c1, c2, h1l = 0.f, h2l = 0.f;
    {
        float hv1 = h01 ? h01[(size_t)(row0 + ru) * 64 + ju] : 0.f;
        _Float16 hh = (_Float16)hv1;
        A1[ru * PADH + 64 + ju] = hh;
        A1[16 * PADH + ru * PADH + 64 + ju] = (_Float16)((hv1 - (float)hh) * 2048.f);
        c1 = c01 ? c01[(size_t)(row0 + ru) * 64 + ju] : 0.f;
        float hv2 = h02 ? h02[(size_t)(row0 + ru) * 64 + ju] : 0.f;
        hh = (_Float16)hv2;
        A2[ru * PADH + 64 + ju] = hh;
        A2[16 * PADH + ru * PADH + 64 + ju] = (_Float16)((hv2 - (float)hh) * 2048.f);
        c2 = c02 ? c02[(size_t)(row0 + ru) * 64 + ju] : 0.f;
    }

    const int aoff = lrow * PADH + lkg * 8;

    for (int i = 0; i <= S; ++i) {
        __syncthreads();   // A1/A2 ready; prev gb consumers done
        const bool doL1 = (i < S), doL2 = (i > 0);

        // prefetch x(i+1) (1 f32/thread); drains under the GEMM phase
        float xn = 0.f;
        if (i + 1 < S) {
            const float* pn = (mode == 1)
                ? (inseq + ((size_t)(row0 + rx) * S + i) * 64)        // target[i]
                : (inseq + ((size_t)(row0 + rx) * S + (i + 1)) * 64);
            xn = pn[jx];
        }

        if (doL1) {   // GEMM1: gates1 = A1 @ W1^T
            f32x4 a0[2], a1[2];
            #pragma unroll
            for (int nt = 0; nt < 2; ++nt) {
                a0[nt] = (f32x4){bs1[nt], bs1[nt], bs1[nt], bs1[nt]};
                a1[nt] = (f32x4){0.f, 0.f, 0.f, 0.f};
            }
            #pragma unroll
            for (int kt = 0; kt < 4; ++kt) {
                half8 ah = *(const half8*)&A1[aoff + kt * 32];
                half8 al = *(const half8*)&A1[16 * PADH + aoff + kt * 32];
                #pragma unroll
                for (int nt = 0; nt < 2; ++nt) {
                    a0[nt] = __builtin_amdgcn_mfma_f32_16x16x32_f16(ah, w1hi[kt][nt], a0[nt], 0, 0, 0);
                    a1[nt] = __builtin_amdgcn_mfma_f32_16x16x32_f16(ah, w1lo[kt][nt], a1[nt], 0, 0, 0);
                    a1[nt] = __builtin_amdgcn_mfma_f32_16x16x32_f16(al, w1hi[kt][nt], a1[nt], 0, 0, 0);
                }
            }
            if (lkg < 2) {   // only rows 0..7 are real
                #pragma unroll
                for (int nt = 0; nt < 2; ++nt) {
                    f32x4 g = a0[nt] + a1[nt] * IC_;
                    const int col = w * 32 + nt * 16 + lrow;
                    #pragma unroll
                    for (int q = 0; q < 4; ++q)
                        gb1[(lkg * 4 + q) * GBS + col] = g[q];
                }
            }
        }
        if (doL2) {   // GEMM2: gates2 = A2 @ W2^T
            f32x4 a0[2], a1[2];
            #pragma unroll
            for (int nt = 0; nt < 2; ++nt) {
                a0[nt] = (f32x4){bs2[nt], bs2[nt], bs2[nt], bs2[nt]};
                a1[nt] = (f32x4){0.f, 0.f, 0.f, 0.f};
            }
            #pragma unroll
            for (int kt = 0; kt < 4; ++kt) {
                half8 ah = *(const half8*)&A2[aoff + kt * 32];
                half8 al = *(const half8*)&A2[16 * PADH + aoff + kt * 32];
                #pragma unroll
                for (int nt = 0; nt < 2; ++nt) {
                    a0[nt] = __builtin_amdgcn_mfma_f32_16x16x32_f16(ah, w2hi[kt][nt], a0[nt], 0, 0, 0);
                    a1[nt] = __builtin_amdgcn_mfma_f32_16x16x32_f16(ah, w2lo[kt][nt], a1[nt], 0, 0, 0);
                    a1[nt] = __builtin_amdgcn_mfma_f32_16x16x32_f16(al, w2hi[kt][nt], a1[nt], 0, 0, 0);
                }
            }
            if (lkg < 2) {
                #pragma unroll
                for (int nt = 0; nt < 2; ++nt) {
                    f32x4 g = a0[nt] + a1[nt] * IC_;
                    const int col = w * 32 + nt * 16 + lrow;
                    #pragma unroll
                    for (int q = 0; q < 4; ++q)
                        gb2[(lkg * 4 + q) * GBS + col] = g[q];
                }
            }
        }
        __syncthreads();   // gb ready; A reads drained

        if (doL1) {   // cell1 (row ru): h1(i) -> A1 h-part AND A2 x-part
            float gi = gb1[ru * GBS +   0 + ju];
            float gf = gb1[ru * GBS +  64 + ju];
            float gg = gb1[ru * GBS + 128 + ju];
            float go = gb1[ru * GBS + 192 + ju];
            c1 = fsig(gf) * c1 + fsig(gi) * ftanh(gg);
            float hv = fsig(go) * ftanh(c1);
            h1l = hv;
            _Float16 hh = (_Float16)hv;
            _Float16 hl = (_Float16)((hv - (float)hh) * 2048.f);
            A1[ru * PADH + 64 + ju] = hh;
            A1[16 * PADH + ru * PADH + 64 + ju] = hl;
            A2[ru * PADH + ju] = hh;
            A2[16 * PADH + ru * PADH + ju] = hl;
            if (i + 1 < S) {   // stage x(i+1)
                _Float16 xh = (_Float16)xn;
                A1[rx * PADH + jx] = xh;
                A1[16 * PADH + rx * PADH + jx] = (_Float16)((xn - (float)xh) * 2048.f);
            }
        }
        if (doL2) {   // cell2 (row ru): h2(i-1) -> A2 h-part + outseq2
            float gi = gb2[ru * GBS +   0 + ju];
            float gf = gb2[ru * GBS +  64 + ju];
            float gg = gb2[ru * GBS + 128 + ju];
            float go = gb2[ru * GBS + 192 + ju];
            c2 = fsig(gf) * c2 + fsig(gi) * ftanh(gg);
            float hv = fsig(go) * ftanh(c2);
            h2l = hv;
            _Float16 hh = (_Float16)hv;
            A2[ru * PADH + 64 + ju] = hh;
            A2[16 * PADH + ru * PADH + 64 + ju] = (_Float16)((hv - (float)hh) * 2048.f);
            outseq2[((size_t)(row0 + ru) * S + (i - 1)) * 64 + ju] = hv;
        }
    }
    if (hf1) {
        hf1[(size_t)(row0 + ru) * 64 + ju] = h1l;
        cf1[(size_t)(row0 + ru) * 64 + ju] = c1;
        hf2[(size_t)(row0 + ru) * 64 + ju] = h2l;
        cf2[(size_t)(row0 + ru) * 64 + ju] = c2;
    }
}

// ---------------------------------------------------------------------------
// Helper: stage a fp32 row-block into hi/lo fp16 LDS planes [R][72] (attn0)
// ---------------------------------------------------------------------------
__device__ __forceinline__ void stage_split(const float* __restrict__ src,
                                            _Float16* dst, int plane,
                                            int row, int c0) {
    #pragma unroll
    for (int u = 0; u < 4; ++u) {
        float4 v = *(const float4*)(src + u * 4);
        half4 hi, lo;
        hi[0] = (_Float16)v.x; lo[0] = (_Float16)((v.x - (float)hi[0]) * 2048.f);
        hi[1] = (_Float16)v.y; lo[1] = (_Float16)((v.y - (float)hi[1]) * 2048.f);
        hi[2] = (_Float16)v.z; lo[2] = (_Float16)((v.z - (float)hi[2]) * 2048.f);
        hi[3] = (_Float16)v.w; lo[3] = (_Float16)((v.w - (float)hi[3]) * 2048.f);
        *(half4*)&dst[row * 72 + c0 + u * 4] = hi;
        *(half4*)&dst[plane + row * 72 + c0 + u * 4] = lo;
    }
}

// ---------------------------------------------------------------------------
// Self-attention, last query only (round-3 known-good).
// ---------------------------------------------------------------------------
__global__ __launch_bounds__(256) void attn0_mfma(
    const float* __restrict__ encout,
    const _Float16* __restrict__ wqkvh,
    const float* __restrict__ bqkv,
    const float* __restrict__ Wqkv,
    const float* __restrict__ Wo,
    const float* __restrict__ bo,
    float* __restrict__ a0last)
{
    __shared__ __align__(16) _Float16 E16[2 * 4608];
    __shared__ __align__(16) _Float16 K16[2 * 4608];
    __shared__ __align__(16) _Float16 V16[4608];
    __shared__ float qv[64];
    __shared__ float wrow[4 * 68];
    __shared__ float ov[64];

    const int b = blockIdx.x, tid = threadIdx.x;
    const int w = tid >> 6, l = tid & 63, lr = l & 15, lkg = l >> 4;

    {
        int row = tid >> 2, c0 = (tid & 3) * 16;
        stage_split(encout + (size_t)b * 4096 + row * 64 + c0, E16, 4608, row, c0);
    }
    __syncthreads();

    for (int tt = w; tt < 8; tt += 4) {
        const int kind = (tt < 4) ? 0 : 1;
        const int mrow = (kind ? tt - 4 : tt) * 16;
        const int wrowB = kind ? 128 : 64;
        half8 ah[2], al[2];
        #pragma unroll
        for (int kt = 0; kt < 2; ++kt) {
            int ao = (mrow + lr) * 72 + kt * 32 + lkg * 8;
            ah[kt] = *(const half8*)&E16[ao];
            al[kt] = *(const half8*)&E16[4608 + ao];
        }
        #pragma unroll
        for (int nt = 0; nt < 4; ++nt) {
            const int col = nt * 16 + lr;
            const float bv = bqkv[wrowB + col];
            f32x4 a0 = (f32x4){bv, bv, bv, bv};
            f32x4 a1 = (f32x4){0.f, 0.f, 0.f, 0.f};
            #pragma unroll
            for (int kt = 0; kt < 2; ++kt) {
                const _Float16* wp = wqkvh + (size_t)(wrowB + col) * 64 + kt * 32 + lkg * 8;
                half8 bh = *(const half8*)wp;
                half8 bl = *(const half8*)(wp + 12288);
                a0 = __builtin_amdgcn_mfma_f32_16x16x32_f16(ah[kt], bh, a0, 0, 0, 0);
                a1 = __builtin_amdgcn_mfma_f32_16x16x32_f16(ah[kt], bl, a1, 0, 0, 0);
                a1 = __builtin_amdgcn_mfma_f32_16x16x32_f16(al[kt], bh, a1, 0, 0, 0);
            }
            #pragma unroll
            for (int i = 0; i < 4; ++i) {
                float g = a0[i] + a1[i] * IC_;
                int r = mrow + lkg * 4 + i;
                if (kind == 0) {
                    _Float16 gh = (_Float16)g;
                    K16[r * 72 + col] = gh;
                    K16[4608 + r * 72 + col] = (_Float16)((g - (float)gh) * 2048.f);
                } else {
                    V16[r * 72 + col] = (_Float16)g;
                }
            }
        }
    }
    if (w == 3) {
        float a = bqkv[l];
        for (int k = 0; k < 64; ++k) {
            float e = (float)E16[63 * 72 + k] + (float)E16[4608 + 63 * 72 + k] * IC_;
            a += e * Wqkv[l * 64 + k];
        }
        qv[l] = a;
    }
    __syncthreads();

    {
        const int h = tid >> 6, kv = tid & 63;
        float s = 0.f;
        #pragma unroll
        for (int d = 0; d < 16; ++d) {
            float kk = (float)K16[kv * 72 + h * 16 + d]
                     + (float)K16[4608 + kv * 72 + h * 16 + d] * IC_;
            s += qv[h * 16 + d] * kk;
        }
        s *= 0.25f;
        float m = s;
        #pragma unroll
        for (int off = 32; off; off >>= 1) m = fmaxf(m, __shfl_xor(m, off));
        float e = __expf(s - m);
        float sum = e;
        #pragma unroll
        for (int off = 32; off; off >>= 1) sum += __shfl_xor(sum, off);
        wrow[h * 68 + kv] = e / sum;
    }
    __syncthreads();
    if (tid < 64) {
        const int h = tid >> 4, d = tid & 15;
        float o = 0.f;
        for (int kv = 0; kv < 64; ++kv)
            o += wrow[h * 68 + kv] * (float)V16[kv * 72 + h * 16 + d];
        ov[tid] = o;
    }
    __syncthreads();
    if (tid < 64) {
        float a = bo[tid];
        for (int k = 0; k < 64; ++k) a += ov[k] * Wo[tid * 64 + k];
        a0last[(size_t)b * 64 + tid] = a;
    }
}

// ---------------------------------------------------------------------------
// Cross-attention v2 (round-4 known-good): one b per block, S^T scores,
// no atomics, 4 barriers, 40960 B dynamic LDS.
// ---------------------------------------------------------------------------
__global__ __launch_bounds__(256, 4) void cross_attn_v2(
    const float* __restrict__ encout, const float* __restrict__ decout,
    const _Float16* __restrict__ wqkvh, const float* __restrict__ bqkv,
    _Float16* __restrict__ AOg, float* __restrict__ attnw)
{
    extern __shared__ __align__(16) char smem[];
    _Float16* E  = (_Float16*)(smem);
    _Float16* D  = (_Float16*)(smem + 9216);
    _Float16* K  = (_Float16*)(smem + 16128);
    _Float16* Q  = (_Float16*)(smem + 25344);
    _Float16* VT = (_Float16*)(smem + 32256);

    const int b = blockIdx.x, tid = threadIdx.x;
    const int w = tid >> 6, l = tid & 63, lr = l & 15, lkg = l >> 4;
    const int h = w;

    {
        int row = tid >> 2, c0 = (tid & 3) * 16;
        const float* ep = encout + (size_t)b * 4096 + row * 64 + c0;
        half8 v0, v1;
        #pragma unroll
        for (int j = 0; j < 8; ++j) v0[j] = (_Float16)ep[j];
        #pragma unroll
        for (int j = 0; j < 8; ++j) v1[j] = (_Float16)ep[8 + j];
        *(half8*)&E[row * 72 + c0] = v0;
        *(half8*)&E[row * 72 + c0 + 8] = v1;
        if (row < 48) {
            const float* dp = decout + (size_t)b * 3072 + row * 64 + c0;
            half8 u0, u1;
            #pragma unroll
            for (int j = 0; j < 8; ++j) u0[j] = (_Float16)dp[j];
            #pragma unroll
            for (int j = 0; j < 8; ++j) u1[j] = (_Float16)dp[8 + j];
            *(half8*)&D[row * 72 + c0] = u0;
            *(half8*)&D[row * 72 + c0 + 8] = u1;
        }
    }
    __syncthreads();

    for (int tt = w; tt < 11; tt += 4) {
        const int kind = (tt < 4) ? 0 : ((tt < 8) ? 1 : 2);
        const int mrow = ((kind == 0) ? tt : (kind == 1) ? tt - 4 : tt - 8) * 16;
        const int wrowB = (kind == 0) ? 64 : ((kind == 1) ? 128 : 0);
        const _Float16* S = (kind == 2) ? D : E;
        half8 ah[2];
        #pragma unroll
        for (int kt = 0; kt < 2; ++kt)
            ah[kt] = *(const half8*)&S[(mrow + lr) * 72 + kt * 32 + lkg * 8];
        #pragma unroll
        for (int nt = 0; nt < 4; ++nt) {
            const int col = nt * 16 + lr;
            const float bv = bqkv[wrowB + col];
            f32x4 a0 = (f32x4){bv, bv, bv, bv};
            #pragma unroll
            for (int kt = 0; kt < 2; ++kt) {
                half8 bh = *(const half8*)&wqkvh[(size_t)(wrowB + col) * 64 + kt * 32 + lkg * 8];
                a0 = __builtin_amdgcn_mfma_f32_16x16x32_f16(ah[kt], bh, a0, 0, 0, 0);
            }
            if (kind == 1) {
                half4 p;
                #pragma unroll
                for (int i = 0; i < 4; ++i) p[i] = (_Float16)a0[i];
                *(half4*)&VT[col * 68 + mrow + lkg * 4] = p;
            } else {
                _Float16* dst = (kind == 0) ? K : Q;
                #pragma unroll
                for (int i = 0; i < 4; ++i)
                    dst[(mrow + lkg * 4 + i) * 72 + col] = (_Float16)a0[i];
            }
        }
    }
    __syncthreads();

    const half8 z = {0, 0, 0, 0, 0, 0, 0, 0};
    half8 ka[4], qb[3];
    #pragma unroll
    for (int kvt = 0; kvt < 4; ++kvt)
        ka[kvt] = (lkg < 2) ? *(const half8*)&K[(kvt * 16 + lr) * 72 + h * 16 + lkg * 8] : z;
    #pragma unroll
    for (int qt = 0; qt < 3; ++qt)
        qb[qt] = (lkg < 2) ? *(const half8*)&Q[(qt * 16 + lr) * 72 + h * 16 + lkg * 8] : z;
    __syncthreads();

    _Float16* strip = (_Float16*)(smem + ((h == 0) ? 0 : (h == 1) ? 9216
                                        : (h == 2) ? 16128 : 25344));
    {
        f32x4 s[3][4];
        #pragma unroll
        for (int qt = 0; qt < 3; ++qt) {
            #pragma unroll
            for (int kvt = 0; kvt < 4; ++kvt) {
                f32x4 a0 = (f32x4){0.f, 0.f, 0.f, 0.f};
                a0 = __builtin_amdgcn_mfma_f32_16x16x32_f16(ka[kvt], qb[qt], a0, 0, 0, 0);
                s[qt][kvt] = a0 * 0.25f;
            }
            float m = s[qt][0][0];
            #pragma unroll
            for (int kvt = 0; kvt < 4; ++kvt)
                #pragma unroll
                for (int i = 0; i < 4; ++i) m = fmaxf(m, s[qt][kvt][i]);
            m = fmaxf(m, __shfl_xor(m, 16));
            m = fmaxf(m, __shfl_xor(m, 32));
            float sum = 0.f;
            #pragma unroll
            for (int kvt = 0; kvt < 4; ++kvt)
                #pragma unroll
                for (int i = 0; i < 4; ++i) {
                    float e = __expf(s[qt][kvt][i] - m);
                    s[qt][kvt][i] = e;
                    sum += e;
                }
            sum += __shfl_xor(sum, 16);
            sum += __shfl_xor(sum, 32);
            const float r = 1.0f / sum;
            #pragma unroll
            for (int kvt = 0; kvt < 4; ++kvt) {
                half4 p;
                #pragma unroll
                for (int i = 0; i < 4; ++i) p[i] = (_Float16)(s[qt][kvt][i] * r);
                *(half4*)&strip[(qt * 16 + lr) * 72 + kvt * 16 + lkg * 4] = p;
            }
        }
    }
    {
        half8 vb[2];
        #pragma unroll
        for (int kt = 0; kt < 2; ++kt) {
            half4 lo4 = *(const half4*)&VT[(h * 16 + lr) * 68 + kt * 32 + lkg * 8];
            half4 hi4 = *(const half4*)&VT[(h * 16 + lr) * 68 + kt * 32 + lkg * 8 + 4];
            #pragma unroll
            for (int j = 0; j < 4; ++j) { vb[kt][j] = lo4[j]; vb[kt][4 + j] = hi4[j]; }
        }
        #pragma unroll
        for (int qt = 0; qt < 3; ++qt) {
            f32x4 acc = (f32x4){0.f, 0.f, 0.f, 0.f};
            #pragma unroll
            for (int kt = 0; kt < 2; ++kt) {
                half8 wa = *(const half8*)&strip[(qt * 16 + lr) * 72 + kt * 32 + lkg * 8];
                acc = __builtin_amdgcn_mfma_f32_16x16x32_f16(wa, vb[kt], acc, 0, 0, 0);
            }
            #pragma unroll
            for (int i = 0; i < 4; ++i)
                AOg[((size_t)b * 48 + qt * 16 + lkg * 4 + i) * 64 + h * 16 + lr] =
                    (_Float16)acc[i];
        }
    }
    __syncthreads();

    {
        const _Float16* s0 = (const _Float16*)(smem);
        const _Float16* s1 = (const _Float16*)(smem + 9216);
        const _Float16* s2 = (const _Float16*)(smem + 16128);
        const _Float16* s3 = (const _Float16*)(smem + 25344);
        #pragma unroll
        for (int it = 0; it < 12; ++it) {
            int idx = tid + it * 256;
            int o = (idx >> 6) * 72 + (idx & 63);
            attnw[(size_t)b * 3072 + idx] =
                0.25f * ((float)s0[o] + (float)s1[o] + (float)s2[o] + (float)s3[o]);
        }
    }
}

// ---------------------------------------------------------------------------
// Batched out-proj + FC1(relu) + FC2. 64 rows/block, zero barriers.
// ---------------------------------------------------------------------------
__global__ __launch_bounds__(256) void proj_fc_kernel(
    const _Float16* __restrict__ AOg,
    const _Float16* __restrict__ woh, const float* __restrict__ bo,
    const _Float16* __restrict__ w1h, const float* __restrict__ b1,
    const float* __restrict__ W2,     const float* __restrict__ b2,
    float* __restrict__ pred)
{
    __shared__ __align__(16) _Float16 obuf[4][16 * 72];
    __shared__ float h1buf[4][16 * 36];
    const int tid = threadIdx.x;
    const int w = tid >> 6, l = tid & 63, lr = l & 15, lkg = l >> 4;
    const size_t r0 = (size_t)blockIdx.x * 64 + w * 16;

    half8 ah[2];
    #pragma unroll
    for (int kt = 0; kt < 2; ++kt)
        ah[kt] = *(const half8*)&AOg[(r0 + lr) * 64 + kt * 32 + lkg * 8];
    #pragma unroll
    for (int nt = 0; nt < 4; ++nt) {
        const int col = nt * 16 + lr;
        const float bv = bo[col];
        f32x4 a0 = (f32x4){bv, bv, bv, bv};
        #pragma unroll
        for (int kt = 0; kt < 2; ++kt) {
            half8 bh = *(const half8*)&woh[(size_t)col * 64 + kt * 32 + lkg * 8];
            a0 = __builtin_amdgcn_mfma_f32_16x16x32_f16(ah[kt], bh, a0, 0, 0, 0);
        }
        #pragma unroll
        for (int i = 0; i < 4; ++i)
            obuf[w][(lkg * 4 + i) * 72 + col] = (_Float16)a0[i];
    }
    half8 oh[2];
    #pragma unroll
    for (int kt = 0; kt < 2; ++kt)
        oh[kt] = *(const half8*)&obuf[w][lr * 72 + kt * 32 + lkg * 8];
    #pragma unroll
    for (int nt = 0; nt < 2; ++nt) {
        const int m = nt * 16 + lr;
        const float bv = b1[m];
        f32x4 a0 = (f32x4){bv, bv, bv, bv};
        #pragma unroll
        for (int kt = 0; kt < 2; ++kt) {
            half8 bh = *(const half8*)&w1h[(size_t)m * 64 + kt * 32 + lkg * 8];
            a0 = __builtin_amdgcn_mfma_f32_16x16x32_f16(oh[kt], bh, a0, 0, 0, 0);
        }
        #pragma unroll
        for (int i = 0; i < 4; ++i)
            h1buf[w][(lkg * 4 + i) * 36 + m] = fmaxf(a0[i], 0.f);
    }
    if (l < 48) {
        const int q = l / 3, n = l - 3 * q;
        float a = b2[n];
        #pragma unroll
        for (int m2 = 0; m2 < 32; ++m2)
            a += h1buf[w][q * 36 + m2] * W2[n * 32 + m2];
        pred[(r0 + q) * 3 + n] = a;
    }
}

// ---------------------------------------------------------------------------
extern "C" void kernel_launch(void* const* d_in, const int* in_sizes, int n_in,
                              void* d_out, int out_size, void* d_ws, size_t ws_size,
                              hipStream_t stream) {
    const float* x      = (const float*)d_in[0];
    const float* target = (const float*)d_in[1];
    const float* eWih0 = (const float*)d_in[2],  *eWhh0 = (const float*)d_in[3];
    const float* ebih0 = (const float*)d_in[4],  *ebhh0 = (const float*)d_in[5];
    const float* eWih1 = (const float*)d_in[6],  *eWhh1 = (const float*)d_in[7];
    const float* ebih1 = (const float*)d_in[8],  *ebhh1 = (const float*)d_in[9];
    const float* dWih0 = (const float*)d_in[10], *dWhh0 = (const float*)d_in[11];
    const float* dbih0 = (const float*)d_in[12], *dbhh0 = (const float*)d_in[13];
    const float* dWih1 = (const float*)d_in[14], *dWhh1 = (const float*)d_in[15];
    const float* dbih1 = (const float*)d_in[16], *dbhh1 = (const float*)d_in[17];
    const float* Wqkv = (const float*)d_in[18], *bqkv = (const float*)d_in[19];
    const float* Wo   = (const float*)d_in[20], *bo   = (const float*)d_in[21];
    const float* W1   = (const float*)d_in[22], *b1   = (const float*)d_in[23];
    const float* W2   = (const float*)d_in[24], *b2   = (const float*)d_in[25];

    float* ws = (float*)d_ws;
    float* hseq1  = ws;                                   // AOg alias region
    float* encout = hseq1  + (size_t)B_ * L_ * H_;
    float* decout = encout + (size_t)B_ * L_ * H_;
    float* a0last = decout + (size_t)B_ * T_ * H_;
    float* hfin   = a0last + (size_t)B_ * H_;
    float* cfin   = hfin   + (size_t)2 * B_ * H_;
    float* wtg    = cfin   + (size_t)2 * B_ * H_;
    float* auxw   = wtg    + (size_t)4 * 32768;

    _Float16* wh0 = (_Float16*)(wtg);
    _Float16* wh1 = wh0 + 65536;
    _Float16* wh2 = wh1 + 65536;
    _Float16* wh3 = wh2 + 65536;
    _Float16* wqkvh = (_Float16*)auxw;        // [2][192][64]
    _Float16* woh   = wqkvh + 24576;          // [2][64][64]
    _Float16* w1h   = woh + 8192;             // [2][32][64]
    _Float16* AOg   = (_Float16*)hseq1;

    float* pred  = (float*)d_out;
    float* attnw = pred + (size_t)B_ * T_ * 3;

    transpose_w_kernel<<<64, 256, 0, stream>>>(eWih0, eWhh0, wh0);
    transpose_w_kernel<<<64, 256, 0, stream>>>(eWih1, eWhh1, wh1);
    transpose_w_kernel<<<64, 256, 0, stream>>>(dWih0, dWhh0, wh2);
    transpose_w_kernel<<<64, 256, 0, stream>>>(dWih1, dWhh1, wh3);
    split_aux_kernel<<<72, 256, 0, stream>>>(Wqkv, Wo, W1, wqkvh, woh, w1h);

    // fused encoder (both layers, skewed); 512 blocks -> 2/CU
    lstm2_mfma_kernel<<<B_ / ROWS, 512, 0, stream>>>(
        x, nullptr, wh0, ebih0, ebhh0, wh1, ebih1, ebhh1,
        nullptr, nullptr, nullptr, nullptr,
        encout, hfin, cfin, hfin + (size_t)B_ * H_, cfin + (size_t)B_ * H_, L_, 0);
    // self-attn, last query
    attn0_mfma<<<B_, 256, 0, stream>>>(encout, wqkvh, bqkv, Wqkv, Wo, bo, a0last);
    // fused decoder
    lstm2_mfma_kernel<<<B_ / ROWS, 512, 0, stream>>>(
        target, a0last, wh2, dbih0, dbhh0, wh3, dbih1, dbhh1,
        hfin, cfin, hfin + (size_t)B_ * H_, cfin + (size_t)B_ * H_,
        decout, nullptr, nullptr, nullptr, nullptr, T_, 1);
    // cross-attention -> AOg, attnw
    cross_attn_v2<<<B_, 256, 40960, stream>>>(
        encout, decout, wqkvh, bqkv, AOg, attnw);
    // out-proj + FC1 + FC2 -> pred
    proj_fc_kernel<<<(B_ * T_) / 64, 256, 0, stream>>>(
        AOg, woh, bo, w1h, b1, W2, b2, pred);
}

// Round 8
// 415.042 us; speedup vs baseline: 3.3622x; 1.5700x over previous
//
#include <hip/hip_runtime.h>
#include <hip/hip_bf16.h>
#include <cstddef>

// ---------------------------------------------------------------------------
// LSTMSeq2Seq: B=4096, L=64, T=48, H=64, NH=4, HD=16, NQ=3
// Round 8: layer-split 16-wave LSTM block (1024 thr, ROWS=16) -> 64 weight
// regs/wave, 4 waves/SIMD in one block. L1/L2 GEMMs run in parallel waves.
// ---------------------------------------------------------------------------

#define B_   4096
#define L_   64
#define T_   48
#define H_   64
#define ROWS 16      // batch rows per LSTM block
#define PADH 136     // LSTM A row pad (halves)
#define GBS  260     // gb row stride (floats): 2-way max on reads/writes

using half8  = __attribute__((ext_vector_type(8))) _Float16;
using half4  = __attribute__((ext_vector_type(4))) _Float16;
using f32x4  = __attribute__((ext_vector_type(4))) float;
using f32x2  = __attribute__((ext_vector_type(2))) float;

#define IC_ 4.8828125e-4f   // 2^-11

// native-rate transcendentals (v_exp_f32 + v_rcp_f32); overflow-safe forms
__device__ __forceinline__ float fsig(float x) {
    return __builtin_amdgcn_rcpf(1.0f + __expf(-x));
}
__device__ __forceinline__ float ftanh(float x) {
    float e = __expf(-2.0f * fabsf(x));            // e in (0,1], never overflows
    float r = (1.0f - e) * __builtin_amdgcn_rcpf(1.0f + e);
    return copysignf(r, x);
}

// ---------------------------------------------------------------------------
// LSTM weight split (one-time): whalf[split][gate_row 256][k 128]
// ---------------------------------------------------------------------------
__global__ void transpose_w_kernel(const float* __restrict__ Wih,
                                   const float* __restrict__ Whh,
                                   _Float16* __restrict__ out) {
    int idx = blockIdx.x * 256 + threadIdx.x;
    if (idx >= 16384) return;
    int r = idx >> 6, k = idx & 63;
    float wi = Wih[idx];
    _Float16 hi = (_Float16)wi;
    out[r * 128 + k] = hi;
    out[32768 + r * 128 + k] = (_Float16)((wi - (float)hi) * 2048.0f);
    float wh = Whh[idx];
    hi = (_Float16)wh;
    out[r * 128 + 64 + k] = hi;
    out[32768 + r * 128 + 64 + k] = (_Float16)((wh - (float)hi) * 2048.0f);
}

// Attention weight splits: wqkvh[2][192][64], woh[2][64][64], w1h[2][32][64]
__global__ void split_aux_kernel(const float* __restrict__ Wqkv,
                                 const float* __restrict__ Wo,
                                 const float* __restrict__ W1,
                                 _Float16* __restrict__ wqkvh,
                                 _Float16* __restrict__ woh,
                                 _Float16* __restrict__ w1h) {
    int idx = blockIdx.x * 256 + threadIdx.x;
    if (idx < 12288) {
        float v = Wqkv[idx]; _Float16 h = (_Float16)v;
        wqkvh[idx] = h; wqkvh[12288 + idx] = (_Float16)((v - (float)h) * 2048.f);
    } else if (idx < 16384) {
        int i = idx - 12288;
        float v = Wo[i]; _Float16 h = (_Float16)v;
        woh[i] = h; woh[4096 + i] = (_Float16)((v - (float)h) * 2048.f);
    } else if (idx < 18432) {
        int i = idx - 16384;
        float v = W1[i]; _Float16 h = (_Float16)v;
        w1h[i] = h; w1h[2048 + i] = (_Float16)((v - (float)h) * 2048.f);
    }
}

// ---------------------------------------------------------------------------
// Fused 2-layer LSTM, skewed, layer-split waves.
// 256 blocks x 1024 threads (16 waves, 4/SIMD). Waves 0-7: layer-1 GEMM
// (32 gate cols each); waves 8-15: layer-2 GEMM. Cell phase: waves 0-7 do
// layer-1 cells, 8-15 layer-2 cells (2 cells/thread: rows ru, ru+8).
// Weight fragments: 16 half8 = 64 VGPRs/wave -> total ~115 <= 128 budget.
// ---------------------------------------------------------------------------
__global__ __launch_bounds__(1024, 4) void lstm2_mfma_kernel(
    const float* __restrict__ inseq,
    const float* __restrict__ in0,
    const _Float16* __restrict__ w1half,
    const float* __restrict__ b1ihp, const float* __restrict__ b1hhp,
    const _Float16* __restrict__ w2half,
    const float* __restrict__ b2ihp, const float* __restrict__ b2hhp,
    const float* __restrict__ h01, const float* __restrict__ c01,
    const float* __restrict__ h02, const float* __restrict__ c02,
    float* __restrict__ outseq2,
    float* __restrict__ hf1, float* __restrict__ cf1,
    float* __restrict__ hf2, float* __restrict__ cf2,
    int S, int mode)
{
    __shared__ __align__(16) _Float16 A1[2 * 16 * PADH];   // [plane][row16][k]
    __shared__ __align__(16) _Float16 A2[2 * 16 * PADH];
    __shared__ __align__(16) float gb1[ROWS * GBS];        // [row16][gatecol]
    __shared__ __align__(16) float gb2[ROWS * GBS];

    const int tid  = threadIdx.x;
    const int w    = tid >> 6;          // 0..15
    const int l    = tid & 63;
    const int lrow = l & 15;
    const int lkg  = l >> 4;
    const int row0 = blockIdx.x * ROWS;

    const bool isL2w = (w >= 8);
    const int  wl    = w & 7;           // col-group within the layer

    // --- this wave's layer weights (16 half8 = 64 VGPRs) --------------------
    const _Float16* wsrc = isL2w ? w2half : w1half;
    const float* bihp = isL2w ? b2ihp : b1ihp;
    const float* bhhp = isL2w ? b2hhp : b1hhp;
    half8 whi[4][2], wlo[4][2];
    #pragma unroll
    for (int kt = 0; kt < 4; ++kt)
        #pragma unroll
        for (int nt = 0; nt < 2; ++nt) {
            const int col = wl * 32 + nt * 16 + lrow;
            const size_t off = (size_t)col * 128 + kt * 32 + lkg * 8;
            whi[kt][nt] = *(const half8*)&wsrc[off];
            wlo[kt][nt] = *(const half8*)&wsrc[32768 + off];
        }
    float bs[2];
    #pragma unroll
    for (int nt = 0; nt < 2; ++nt) {
        const int col = wl * 32 + nt * 16 + lrow;
        bs[nt] = bihp[col] + bhhp[col];
    }

    // maps: x staging (1 value/thread), cells (layer cl, rows ru & ru+8)
    const int rx = tid >> 6, jx = tid & 63;
    const int cl = tid >> 9, ju = tid & 63, ru = (tid >> 6) & 7;
    _Float16* Ah = cl ? A2 : A1;                     // own layer's h-target

    // ---- prologue ----------------------------------------------------------
    {   // x(0) into A1 (all threads, one value each)
        const float* p0 = (mode == 1) ? (in0 + (size_t)(row0 + rx) * 64)
                                      : (inseq + (size_t)(row0 + rx) * S * 64);
        float v = p0[jx];
        _Float16 hi = (_Float16)v;
        A1[rx * PADH + jx] = hi;
        A1[16 * PADH + rx * PADH + jx] = (_Float16)((v - (float)hi) * 2048.f);
    }
    float cc[2], hl[2] = {0.f, 0.f};
    {   // h0/c0 of own layer, rows ru and ru+8
        const float* hsrc = cl ? h02 : h01;
        const float* csrc = cl ? c02 : c01;
        #pragma unroll
        for (int r2 = 0; r2 < 2; ++r2) {
            const int r = ru + 8 * r2;
            float hv = hsrc ? hsrc[(size_t)(row0 + r) * 64 + ju] : 0.f;
            _Float16 hh = (_Float16)hv;
            Ah[r * PADH + 64 + ju] = hh;
            Ah[16 * PADH + r * PADH + 64 + ju] = (_Float16)((hv - (float)hh) * 2048.f);
            cc[r2] = csrc ? csrc[(size_t)(row0 + r) * 64 + ju] : 0.f;
        }
    }

    const int aoff = lrow * PADH + lkg * 8;
    const _Float16* Ag = isL2w ? A2 : A1;            // GEMM source
    float* gbg = isL2w ? gb2 : gb1;                  // GEMM dest

    for (int i = 0; i <= S; ++i) {
        __syncthreads();   // A ready; prev gb consumers done

        // prefetch x(i+1): all threads, 1 value
        float xn = 0.f;
        if (i + 1 < S) {
            const float* pn = (mode == 1)
                ? (inseq + ((size_t)(row0 + rx) * S + i) * 64)        // target[i]
                : (inseq + ((size_t)(row0 + rx) * S + (i + 1)) * 64);
            xn = pn[jx];
        }

        const bool act = isL2w ? (i > 0) : (i < S);
        if (act) {   // GEMM: gates = A @ W^T for this wave's layer/cols
            f32x4 a0[2], a1[2];
            #pragma unroll
            for (int nt = 0; nt < 2; ++nt) {
                a0[nt] = (f32x4){bs[nt], bs[nt], bs[nt], bs[nt]};
                a1[nt] = (f32x4){0.f, 0.f, 0.f, 0.f};
            }
            #pragma unroll
            for (int kt = 0; kt < 4; ++kt) {
                half8 ah = *(const half8*)&Ag[aoff + kt * 32];
                half8 al = *(const half8*)&Ag[16 * PADH + aoff + kt * 32];
                #pragma unroll
                for (int nt = 0; nt < 2; ++nt) {
                    a0[nt] = __builtin_amdgcn_mfma_f32_16x16x32_f16(ah, whi[kt][nt], a0[nt], 0, 0, 0);
                    a1[nt] = __builtin_amdgcn_mfma_f32_16x16x32_f16(ah, wlo[kt][nt], a1[nt], 0, 0, 0);
                    a1[nt] = __builtin_amdgcn_mfma_f32_16x16x32_f16(al, whi[kt][nt], a1[nt], 0, 0, 0);
                }
            }
            #pragma unroll
            for (int nt = 0; nt < 2; ++nt) {
                f32x4 g = a0[nt] + a1[nt] * IC_;
                const int col = wl * 32 + nt * 16 + lrow;
                #pragma unroll
                for (int q = 0; q < 4; ++q)
                    gbg[(lkg * 4 + q) * GBS + col] = g[q];
            }
        }
        __syncthreads();   // gb ready; A reads drained

        // stage x(i+1) into A1 x-part (all threads; A1 reads are drained)
        if (i + 1 < S) {
            _Float16 xh = (_Float16)xn;
            A1[rx * PADH + jx] = xh;
            A1[16 * PADH + rx * PADH + jx] = (_Float16)((xn - (float)xh) * 2048.f);
        }

        if (cl == 0) {
            if (i < S) {   // cell1 rows ru, ru+8: h1(i) -> A1 h-part, A2 x-part
                #pragma unroll
                for (int r2 = 0; r2 < 2; ++r2) {
                    const int r = ru + 8 * r2;
                    float gi = gb1[r * GBS +   0 + ju];
                    float gf = gb1[r * GBS +  64 + ju];
                    float gg = gb1[r * GBS + 128 + ju];
                    float go = gb1[r * GBS + 192 + ju];
                    cc[r2] = fsig(gf) * cc[r2] + fsig(gi) * ftanh(gg);
                    float hv = fsig(go) * ftanh(cc[r2]);
                    hl[r2] = hv;
                    _Float16 hh = (_Float16)hv;
                    _Float16 hlo = (_Float16)((hv - (float)hh) * 2048.f);
                    A1[r * PADH + 64 + ju] = hh;
                    A1[16 * PADH + r * PADH + 64 + ju] = hlo;
                    A2[r * PADH + ju] = hh;
                    A2[16 * PADH + r * PADH + ju] = hlo;
                }
            }
        } else {
            if (i > 0) {   // cell2 rows ru, ru+8: h2(i-1) -> A2 h-part + out
                #pragma unroll
                for (int r2 = 0; r2 < 2; ++r2) {
                    const int r = ru + 8 * r2;
                    float gi = gb2[r * GBS +   0 + ju];
                    float gf = gb2[r * GBS +  64 + ju];
                    float gg = gb2[r * GBS + 128 + ju];
                    float go = gb2[r * GBS + 192 + ju];
                    cc[r2] = fsig(gf) * cc[r2] + fsig(gi) * ftanh(gg);
                    float hv = fsig(go) * ftanh(cc[r2]);
                    hl[r2] = hv;
                    _Float16 hh = (_Float16)hv;
                    A2[r * PADH + 64 + ju] = hh;
                    A2[16 * PADH + r * PADH + 64 + ju] =
                        (_Float16)((hv - (float)hh) * 2048.f);
                    outseq2[((size_t)(row0 + r) * S + (i - 1)) * 64 + ju] = hv;
                }
            }
        }
    }
    if (hf1) {
        float* hdst = cl ? hf2 : hf1;
        float* cdst = cl ? cf2 : cf1;
        #pragma unroll
        for (int r2 = 0; r2 < 2; ++r2) {
            const int r = ru + 8 * r2;
            hdst[(size_t)(row0 + r) * 64 + ju] = hl[r2];
            cdst[(size_t)(row0 + r) * 64 + ju] = cc[r2];
        }
    }
}

// ---------------------------------------------------------------------------
// Helper: stage a fp32 row-block into hi/lo fp16 LDS planes [R][72] (attn0)
// ---------------------------------------------------------------------------
__device__ __forceinline__ void stage_split(const float* __restrict__ src,
                                            _Float16* dst, int plane,
                                            int row, int c0) {
    #pragma unroll
    for (int u = 0; u < 4; ++u) {
        float4 v = *(const float4*)(src + u * 4);
        half4 hi, lo;
        hi[0] = (_Float16)v.x; lo[0] = (_Float16)((v.x - (float)hi[0]) * 2048.f);
        hi[1] = (_Float16)v.y; lo[1] = (_Float16)((v.y - (float)hi[1]) * 2048.f);
        hi[2] = (_Float16)v.z; lo[2] = (_Float16)((v.z - (float)hi[2]) * 2048.f);
        hi[3] = (_Float16)v.w; lo[3] = (_Float16)((v.w - (float)hi[3]) * 2048.f);
        *(half4*)&dst[row * 72 + c0 + u * 4] = hi;
        *(half4*)&dst[plane + row * 72 + c0 + u * 4] = lo;
    }
}

// ---------------------------------------------------------------------------
// Self-attention, last query only (round-3 known-good).
// ---------------------------------------------------------------------------
__global__ __launch_bounds__(256) void attn0_mfma(
    const float* __restrict__ encout,
    const _Float16* __restrict__ wqkvh,
    const float* __restrict__ bqkv,
    const float* __restrict__ Wqkv,
    const float* __restrict__ Wo,
    const float* __restrict__ bo,
    float* __restrict__ a0last)
{
    __shared__ __align__(16) _Float16 E16[2 * 4608];
    __shared__ __align__(16) _Float16 K16[2 * 4608];
    __shared__ __align__(16) _Float16 V16[4608];
    __shared__ float qv[64];
    __shared__ float wrow[4 * 68];
    __shared__ float ov[64];

    const int b = blockIdx.x, tid = threadIdx.x;
    const int w = tid >> 6, l = tid & 63, lr = l & 15, lkg = l >> 4;

    {
        int row = tid >> 2, c0 = (tid & 3) * 16;
        stage_split(encout + (size_t)b * 4096 + row * 64 + c0, E16, 4608, row, c0);
    }
    __syncthreads();

    for (int tt = w; tt < 8; tt += 4) {
        const int kind = (tt < 4) ? 0 : 1;
        const int mrow = (kind ? tt - 4 : tt) * 16;
        const int wrowB = kind ? 128 : 64;
        half8 ah[2], al[2];
        #pragma unroll
        for (int kt = 0; kt < 2; ++kt) {
            int ao = (mrow + lr) * 72 + kt * 32 + lkg * 8;
            ah[kt] = *(const half8*)&E16[ao];
            al[kt] = *(const half8*)&E16[4608 + ao];
        }
        #pragma unroll
        for (int nt = 0; nt < 4; ++nt) {
            const int col = nt * 16 + lr;
            const float bv = bqkv[wrowB + col];
            f32x4 a0 = (f32x4){bv, bv, bv, bv};
            f32x4 a1 = (f32x4){0.f, 0.f, 0.f, 0.f};
            #pragma unroll
            for (int kt = 0; kt < 2; ++kt) {
                const _Float16* wp = wqkvh + (size_t)(wrowB + col) * 64 + kt * 32 + lkg * 8;
                half8 bh = *(const half8*)wp;
                half8 bl = *(const half8*)(wp + 12288);
                a0 = __builtin_amdgcn_mfma_f32_16x16x32_f16(ah[kt], bh, a0, 0, 0, 0);
                a1 = __builtin_amdgcn_mfma_f32_16x16x32_f16(ah[kt], bl, a1, 0, 0, 0);
                a1 = __builtin_amdgcn_mfma_f32_16x16x32_f16(al[kt], bh, a1, 0, 0, 0);
            }
            #pragma unroll
            for (int i = 0; i < 4; ++i) {
                float g = a0[i] + a1[i] * IC_;
                int r = mrow + lkg * 4 + i;
                if (kind == 0) {
                    _Float16 gh = (_Float16)g;
                    K16[r * 72 + col] = gh;
                    K16[4608 + r * 72 + col] = (_Float16)((g - (float)gh) * 2048.f);
                } else {
                    V16[r * 72 + col] = (_Float16)g;
                }
            }
        }
    }
    if (w == 3) {
        float a = bqkv[l];
        for (int k = 0; k < 64; ++k) {
            float e = (float)E16[63 * 72 + k] + (float)E16[4608 + 63 * 72 + k] * IC_;
            a += e * Wqkv[l * 64 + k];
        }
        qv[l] = a;
    }
    __syncthreads();

    {
        const int h = tid >> 6, kv = tid & 63;
        float s = 0.f;
        #pragma unroll
        for (int d = 0; d < 16; ++d) {
            float kk = (float)K16[kv * 72 + h * 16 + d]
                     + (float)K16[4608 + kv * 72 + h * 16 + d] * IC_;
            s += qv[h * 16 + d] * kk;
        }
        s *= 0.25f;
        float m = s;
        #pragma unroll
        for (int off = 32; off; off >>= 1) m = fmaxf(m, __shfl_xor(m, off));
        float e = __expf(s - m);
        float sum = e;
        #pragma unroll
        for (int off = 32; off; off >>= 1) sum += __shfl_xor(sum, off);
        wrow[h * 68 + kv] = e / sum;
    }
    __syncthreads();
    if (tid < 64) {
        const int h = tid >> 4, d = tid & 15;
        float o = 0.f;
        for (int kv = 0; kv < 64; ++kv)
            o += wrow[h * 68 + kv] * (float)V16[kv * 72 + h * 16 + d];
        ov[tid] = o;
    }
    __syncthreads();
    if (tid < 64) {
        float a = bo[tid];
        for (int k = 0; k < 64; ++k) a += ov[k] * Wo[tid * 64 + k];
        a0last[(size_t)b * 64 + tid] = a;
    }
}

// ---------------------------------------------------------------------------
// Cross-attention v2 (round-4 known-good): one b per block, S^T scores,
// no atomics, 4 barriers, 40960 B dynamic LDS.
// ---------------------------------------------------------------------------
__global__ __launch_bounds__(256, 4) void cross_attn_v2(
    const float* __restrict__ encout, const float* __restrict__ decout,
    const _Float16* __restrict__ wqkvh, const float* __restrict__ bqkv,
    _Float16* __restrict__ AOg, float* __restrict__ attnw)
{
    extern __shared__ __align__(16) char smem[];
    _Float16* E  = (_Float16*)(smem);
    _Float16* D  = (_Float16*)(smem + 9216);
    _Float16* K  = (_Float16*)(smem + 16128);
    _Float16* Q  = (_Float16*)(smem + 25344);
    _Float16* VT = (_Float16*)(smem + 32256);

    const int b = blockIdx.x, tid = threadIdx.x;
    const int w = tid >> 6, l = tid & 63, lr = l & 15, lkg = l >> 4;
    const int h = w;

    {
        int row = tid >> 2, c0 = (tid & 3) * 16;
        const float* ep = encout + (size_t)b * 4096 + row * 64 + c0;
        half8 v0, v1;
        #pragma unroll
        for (int j = 0; j < 8; ++j) v0[j] = (_Float16)ep[j];
        #pragma unroll
        for (int j = 0; j < 8; ++j) v1[j] = (_Float16)ep[8 + j];
        *(half8*)&E[row * 72 + c0] = v0;
        *(half8*)&E[row * 72 + c0 + 8] = v1;
        if (row < 48) {
            const float* dp = decout + (size_t)b * 3072 + row * 64 + c0;
            half8 u0, u1;
            #pragma unroll
            for (int j = 0; j < 8; ++j) u0[j] = (_Float16)dp[j];
            #pragma unroll
            for (int j = 0; j < 8; ++j) u1[j] = (_Float16)dp[8 + j];
            *(half8*)&D[row * 72 + c0] = u0;
            *(half8*)&D[row * 72 + c0 + 8] = u1;
        }
    }
    __syncthreads();

    for (int tt = w; tt < 11; tt += 4) {
        const int kind = (tt < 4) ? 0 : ((tt < 8) ? 1 : 2);
        const int mrow = ((kind == 0) ? tt : (kind == 1) ? tt - 4 : tt - 8) * 16;
        const int wrowB = (kind == 0) ? 64 : ((kind == 1) ? 128 : 0);
        const _Float16* S = (kind == 2) ? D : E;
        half8 ah[2];
        #pragma unroll
        for (int kt = 0; kt < 2; ++kt)
            ah[kt] = *(const half8*)&S[(mrow + lr) * 72 + kt * 32 + lkg * 8];
        #pragma unroll
        for (int nt = 0; nt < 4; ++nt) {
            const int col = nt * 16 + lr;
            const float bv = bqkv[wrowB + col];
            f32x4 a0 = (f32x4){bv, bv, bv, bv};
            #pragma unroll
            for (int kt = 0; kt < 2; ++kt) {
                half8 bh = *(const half8*)&wqkvh[(size_t)(wrowB + col) * 64 + kt * 32 + lkg * 8];
                a0 = __builtin_amdgcn_mfma_f32_16x16x32_f16(ah[kt], bh, a0, 0, 0, 0);
            }
            if (kind == 1) {
                half4 p;
                #pragma unroll
                for (int i = 0; i < 4; ++i) p[i] = (_Float16)a0[i];
                *(half4*)&VT[col * 68 + mrow + lkg * 4] = p;
            } else {
                _Float16* dst = (kind == 0) ? K : Q;
                #pragma unroll
                for (int i = 0; i < 4; ++i)
                    dst[(mrow + lkg * 4 + i) * 72 + col] = (_Float16)a0[i];
            }
        }
    }
    __syncthreads();

    const half8 z = {0, 0, 0, 0, 0, 0, 0, 0};
    half8 ka[4], qb[3];
    #pragma unroll
    for (int kvt = 0; kvt < 4; ++kvt)
        ka[kvt] = (lkg < 2) ? *(const half8*)&K[(kvt * 16 + lr) * 72 + h * 16 + lkg * 8] : z;
    #pragma unroll
    for (int qt = 0; qt < 3; ++qt)
        qb[qt] = (lkg < 2) ? *(const half8*)&Q[(qt * 16 + lr) * 72 + h * 16 + lkg * 8] : z;
    __syncthreads();

    _Float16* strip = (_Float16*)(smem + ((h == 0) ? 0 : (h == 1) ? 9216
                                        : (h == 2) ? 16128 : 25344));
    {
        f32x4 s[3][4];
        #pragma unroll
        for (int qt = 0; qt < 3; ++qt) {
            #pragma unroll
            for (int kvt = 0; kvt < 4; ++kvt) {
                f32x4 a0 = (f32x4){0.f, 0.f, 0.f, 0.f};
                a0 = __builtin_amdgcn_mfma_f32_16x16x32_f16(ka[kvt], qb[qt], a0, 0, 0, 0);
                s[qt][kvt] = a0 * 0.25f;
            }
            float m = s[qt][0][0];
            #pragma unroll
            for (int kvt = 0; kvt < 4; ++kvt)
                #pragma unroll
                for (int i = 0; i < 4; ++i) m = fmaxf(m, s[qt][kvt][i]);
            m = fmaxf(m, __shfl_xor(m, 16));
            m = fmaxf(m, __shfl_xor(m, 32));
            float sum = 0.f;
            #pragma unroll
            for (int kvt = 0; kvt < 4; ++kvt)
                #pragma unroll
                for (int i = 0; i < 4; ++i) {
                    float e = __expf(s[qt][kvt][i] - m);
                    s[qt][kvt][i] = e;
                    sum += e;
                }
            sum += __shfl_xor(sum, 16);
            sum += __shfl_xor(sum, 32);
            const float r = 1.0f / sum;
            #pragma unroll
            for (int kvt = 0; kvt < 4; ++kvt) {
                half4 p;
                #pragma unroll
                for (int i = 0; i < 4; ++i) p[i] = (_Float16)(s[qt][kvt][i] * r);
                *(half4*)&strip[(qt * 16 + lr) * 72 + kvt * 16 + lkg * 4] = p;
            }
        }
    }
    {
        half8 vb[2];
        #pragma unroll
        for (int kt = 0; kt < 2; ++kt) {
            half4 lo4 = *(const half4*)&VT[(h * 16 + lr) * 68 + kt * 32 + lkg * 8];
            half4 hi4 = *(const half4*)&VT[(h * 16 + lr) * 68 + kt * 32 + lkg * 8 + 4];
            #pragma unroll
            for (int j = 0; j < 4; ++j) { vb[kt][j] = lo4[j]; vb[kt][4 + j] = hi4[j]; }
        }
        #pragma unroll
        for (int qt = 0; qt < 3; ++qt) {
            f32x4 acc = (f32x4){0.f, 0.f, 0.f, 0.f};
            #pragma unroll
            for (int kt = 0; kt < 2; ++kt) {
                half8 wa = *(const half8*)&strip[(qt * 16 + lr) * 72 + kt * 32 + lkg * 8];
                acc = __builtin_amdgcn_mfma_f32_16x16x32_f16(wa, vb[kt], acc, 0, 0, 0);
            }
            #pragma unroll
            for (int i = 0; i < 4; ++i)
                AOg[((size_t)b * 48 + qt * 16 + lkg * 4 + i) * 64 + h * 16 + lr] =
                    (_Float16)acc[i];
        }
    }
    __syncthreads();

    {
        const _Float16* s0 = (const _Float16*)(smem);
        const _Float16* s1 = (const _Float16*)(smem + 9216);
        const _Float16* s2 = (const _Float16*)(smem + 16128);
        const _Float16* s3 = (const _Float16*)(smem + 25344);
        #pragma unroll
        for (int it = 0; it < 12; ++it) {
            int idx = tid + it * 256;
            int o = (idx >> 6) * 72 + (idx & 63);
            attnw[(size_t)b * 3072 + idx] =
                0.25f * ((float)s0[o] + (float)s1[o] + (float)s2[o] + (float)s3[o]);
        }
    }
}

// ---------------------------------------------------------------------------
// Batched out-proj + FC1(relu) + FC2. 64 rows/block, zero barriers.
// ---------------------------------------------------------------------------
__global__ __launch_bounds__(256) void proj_fc_kernel(
    const _Float16* __restrict__ AOg,
    const _Float16* __restrict__ woh, const float* __restrict__ bo,
    const _Float16* __restrict__ w1h, const float* __restrict__ b1,
    const float* __restrict__ W2,     const float* __restrict__ b2,
    float* __restrict__ pred)
{
    __shared__ __align__(16) _Float16 obuf[4][16 * 72];
    __shared__ float h1buf[4][16 * 36];
    const int tid = threadIdx.x;
    const int w = tid >> 6, l = tid & 63, lr = l & 15, lkg = l >> 4;
    const size_t r0 = (size_t)blockIdx.x * 64 + w * 16;

    half8 ah[2];
    #pragma unroll
    for (int kt = 0; kt < 2; ++kt)
        ah[kt] = *(const half8*)&AOg[(r0 + lr) * 64 + kt * 32 + lkg * 8];
    #pragma unroll
    for (int nt = 0; nt < 4; ++nt) {
        const int col = nt * 16 + lr;
        const float bv = bo[col];
        f32x4 a0 = (f32x4){bv, bv, bv, bv};
        #pragma unroll
        for (int kt = 0; kt < 2; ++kt) {
            half8 bh = *(const half8*)&woh[(size_t)col * 64 + kt * 32 + lkg * 8];
            a0 = __builtin_amdgcn_mfma_f32_16x16x32_f16(ah[kt], bh, a0, 0, 0, 0);
        }
        #pragma unroll
        for (int i = 0; i < 4; ++i)
            obuf[w][(lkg * 4 + i) * 72 + col] = (_Float16)a0[i];
    }
    half8 oh[2];
    #pragma unroll
    for (int kt = 0; kt < 2; ++kt)
        oh[kt] = *(const half8*)&obuf[w][lr * 72 + kt * 32 + lkg * 8];
    #pragma unroll
    for (int nt = 0; nt < 2; ++nt) {
        const int m = nt * 16 + lr;
        const float bv = b1[m];
        f32x4 a0 = (f32x4){bv, bv, bv, bv};
        #pragma unroll
        for (int kt = 0; kt < 2; ++kt) {
            half8 bh = *(const half8*)&w1h[(size_t)m * 64 + kt * 32 + lkg * 8];
            a0 = __builtin_amdgcn_mfma_f32_16x16x32_f16(oh[kt], bh, a0, 0, 0, 0);
        }
        #pragma unroll
        for (int i = 0; i < 4; ++i)
            h1buf[w][(lkg * 4 + i) * 36 + m] = fmaxf(a0[i], 0.f);
    }
    if (l < 48) {
        const int q = l / 3, n = l - 3 * q;
        float a = b2[n];
        #pragma unroll
        for (int m2 = 0; m2 < 32; ++m2)
            a += h1buf[w][q * 36 + m2] * W2[n * 32 + m2];
        pred[(r0 + q) * 3 + n] = a;
    }
}

// ---------------------------------------------------------------------------
extern "C" void kernel_launch(void* const* d_in, const int* in_sizes, int n_in,
                              void* d_out, int out_size, void* d_ws, size_t ws_size,
                              hipStream_t stream) {
    const float* x      = (const float*)d_in[0];
    const float* target = (const float*)d_in[1];
    const float* eWih0 = (const float*)d_in[2],  *eWhh0 = (const float*)d_in[3];
    const float* ebih0 = (const float*)d_in[4],  *ebhh0 = (const float*)d_in[5];
    const float* eWih1 = (const float*)d_in[6],  *eWhh1 = (const float*)d_in[7];
    const float* ebih1 = (const float*)d_in[8],  *ebhh1 = (const float*)d_in[9];
    const float* dWih0 = (const float*)d_in[10], *dWhh0 = (const float*)d_in[11];
    const float* dbih0 = (const float*)d_in[12], *dbhh0 = (const float*)d_in[13];
    const float* dWih1 = (const float*)d_in[14], *dWhh1 = (const float*)d_in[15];
    const float* dbih1 = (const float*)d_in[16], *dbhh1 = (const float*)d_in[17];
    const float* Wqkv = (const float*)d_in[18], *bqkv = (const float*)d_in[19];
    const float* Wo   = (const float*)d_in[20], *bo   = (const float*)d_in[21];
    const float* W1   = (const float*)d_in[22], *b1   = (const float*)d_in[23];
    const float* W2   = (const float*)d_in[24], *b2   = (const float*)d_in[25];

    float* ws = (float*)d_ws;
    float* hseq1  = ws;                                   // AOg alias region
    float* encout = hseq1  + (size_t)B_ * L_ * H_;
    float* decout = encout + (size_t)B_ * L_ * H_;
    float* a0last = decout + (size_t)B_ * T_ * H_;
    float* hfin   = a0last + (size_t)B_ * H_;
    float* cfin   = hfin   + (size_t)2 * B_ * H_;
    float* wtg    = cfin   + (size_t)2 * B_ * H_;
    float* auxw   = wtg    + (size_t)4 * 32768;

    _Float16* wh0 = (_Float16*)(wtg);
    _Float16* wh1 = wh0 + 65536;
    _Float16* wh2 = wh1 + 65536;
    _Float16* wh3 = wh2 + 65536;
    _Float16* wqkvh = (_Float16*)auxw;        // [2][192][64]
    _Float16* woh   = wqkvh + 24576;          // [2][64][64]
    _Float16* w1h   = woh + 8192;             // [2][32][64]
    _Float16* AOg   = (_Float16*)hseq1;

    float* pred  = (float*)d_out;
    float* attnw = pred + (size_t)B_ * T_ * 3;

    transpose_w_kernel<<<64, 256, 0, stream>>>(eWih0, eWhh0, wh0);
    transpose_w_kernel<<<64, 256, 0, stream>>>(eWih1, eWhh1, wh1);
    transpose_w_kernel<<<64, 256, 0, stream>>>(dWih0, dWhh0, wh2);
    transpose_w_kernel<<<64, 256, 0, stream>>>(dWih1, dWhh1, wh3);
    split_aux_kernel<<<72, 256, 0, stream>>>(Wqkv, Wo, W1, wqkvh, woh, w1h);

    // fused encoder (both layers, layer-split waves); 256 blocks x 1024 thr
    lstm2_mfma_kernel<<<B_ / ROWS, 1024, 0, stream>>>(
        x, nullptr, wh0, ebih0, ebhh0, wh1, ebih1, ebhh1,
        nullptr, nullptr, nullptr, nullptr,
        encout, hfin, cfin, hfin + (size_t)B_ * H_, cfin + (size_t)B_ * H_, L_, 0);
    // self-attn, last query
    attn0_mfma<<<B_, 256, 0, stream>>>(encout, wqkvh, bqkv, Wqkv, Wo, bo, a0last);
    // fused decoder
    lstm2_mfma_kernel<<<B_ / ROWS, 1024, 0, stream>>>(
        target, a0last, wh2, dbih0, dbhh0, wh3, dbih1, dbhh1,
        hfin, cfin, hfin + (size_t)B_ * H_, cfin + (size_t)B_ * H_,
        decout, nullptr, nullptr, nullptr, nullptr, T_, 1);
    // cross-attention -> AOg, attnw
    cross_attn_v2<<<B_, 256, 40960, stream>>>(
        encout, decout, wqkvh, bqkv, AOg, attnw);
    // out-proj + FC1 + FC2 -> pred
    proj_fc_kernel<<<(B_ * T_) / 64, 256, 0, stream>>>(
        AOg, woh, bo, w1h, b1, W2, b2, pred);
}